// Round 9
// baseline (211.197 us; speedup 1.0000x reference)
//
#include <hip/hip_runtime.h>
#include <cstdint>
#include <cstddef>

// fp32 I/O. Internals: bf16 NHC activations + MFMA everywhere.
// mfma_f32_16x16x32_bf16 layouts (HW-verified m89/m120):
//   A: m=lane&15, k=quad*8+j   B: n=lane&15, k=quad*8+j
//   C/D: col(n)=lane&15, row(m)=quad*4+reg
// LDS tiles [row][64] bf16, XOR swizzle applied to the GLOBAL source chunk
// (sg = pg ^ (row&7)) so global_load_lds produces the swizzled image
// (involutive); frag reads conflict-free.
// Softmax: fixed-shift exp2, log2(e)/8 folded into Wq/bq. Split-K additive.
// r2 (220.2us): PV via K=32 MFMA (permlane32/16 P redistribution); li on
// MFMA pipe (ones-B-frag); attn K/V double-buffered, 1 barrier/tile.
// r7/r8 (208.9us, MEASURED WIN +11.3): gemm o-tile 128->64 doubled every
// gemm grid -> 1-3 blocks/CU of latency hiding. attn unchanged 71.8us.
// r9 (same mechanism, one more notch): n-tile 128->64 for the three
// variant-0/2 gemms still at 1-2 blocks/CU (msg 256->512 blocks, h
// 512->1024, W2 256->512; LDS 24->16KB). qkv stays BN=128 (already 3/CU).
// template<int BN>: BN=128 instantiation is byte-equivalent to r8's
// measured kernel.

typedef __attribute__((ext_vector_type(8))) short short8;
typedef __attribute__((ext_vector_type(4))) float floatx4;

union U4 { unsigned int u[4]; short8 s; };

__device__ __forceinline__ unsigned short f2bf(float x) {
  union { float f; unsigned int u; } c; c.f = x;
  unsigned int r = c.u + 0x7FFFu + ((c.u >> 16) & 1u);   // RNE
  return (unsigned short)(r >> 16);
}
__device__ __forceinline__ float bf2f(unsigned short u) {
  union { unsigned int i; float f; } c; c.i = ((unsigned int)u) << 16; return c.f;
}
__device__ __forceinline__ void gload16(const void* g, void* l) {
  __builtin_amdgcn_global_load_lds(
      (const __attribute__((address_space(1))) unsigned int*)g,
      (__attribute__((address_space(3))) unsigned int*)l, 16, 0, 0);
}
// packed f32x2 -> bf16x2 (RNE), lo = s0, hi = s1
__device__ __forceinline__ unsigned int cvtpk(float lo, float hi) {
  unsigned int r;
  asm("v_cvt_pk_bf16_f32 %0, %1, %2" : "=v"(r) : "v"(lo), "v"(hi));
  return r;
}

#define LOG2E_8 0.18033688011112042f

// ---------------------------------------------------------------------------
// Transpose+convert both inputs: [b][c][n] fp32 -> [b][n][c] bf16.
// Grid (N/32, C/32, 2*B): z = which*2 + b.
// ---------------------------------------------------------------------------
__global__ __launch_bounds__(256) void tx_all(
    const float* __restrict__ x, const float* __restrict__ src,
    unsigned short* __restrict__ xb, unsigned short* __restrict__ sb,
    int C, int N)
{
  __shared__ float tile[32][33];
  const int which = blockIdx.z >> 1, b = blockIdx.z & 1;
  const float* X = which ? src : x;
  unsigned short* Y = which ? sb : xb;
  const int n0 = blockIdx.x * 32, c0 = blockIdx.y * 32;
  const int tc = threadIdx.x & 31, tr = threadIdx.x >> 5;
  #pragma unroll
  for (int i = 0; i < 4; ++i)
    tile[tr + i * 8][tc] = X[((size_t)b * C + c0 + tr + i * 8) * N + n0 + tc];
  __syncthreads();
  #pragma unroll
  for (int i = 0; i < 4; ++i)
    Y[((size_t)b * N + n0 + tr + i * 8) * C + c0 + tc] = f2bf(tile[tc][tr + i * 8]);
}

// ---------------------------------------------------------------------------
// All weight+bias converts in ONE dispatch. Grid 2567 blocks.
// wqkv rows head-major (o' = h*64+d reads o = 4*d+h); Wq/bq scaled log2e/8;
// Wm columns head-major.
// ---------------------------------------------------------------------------
__global__ __launch_bounds__(256) void wprep(
    const float* __restrict__ Wq, const float* __restrict__ Wk,
    const float* __restrict__ Wv, const float* __restrict__ Wm,
    const float* __restrict__ W1, const float* __restrict__ W2,
    const float* __restrict__ bq, const float* __restrict__ bk,
    const float* __restrict__ bv, const float* __restrict__ bm,
    const float* __restrict__ b1, const float* __restrict__ b2,
    unsigned short* __restrict__ wqkv, unsigned short* __restrict__ wm_,
    unsigned short* __restrict__ w1_, unsigned short* __restrict__ w2_,
    float* __restrict__ biasb)
{
  const int bid = blockIdx.x, t = threadIdx.x;
  if (bid < 768) {
    const int idx = bid * 256 + t;
    const int op = idx >> 8, ip = idx & 255;
    const int grp = op >> 8, oo = op & 255;
    const int o = 4 * (oo & 63) + (oo >> 6);
    const float* W = grp == 0 ? Wq : grp == 1 ? Wk : Wv;
    const float sc = grp == 0 ? LOG2E_8 : 1.f;
    wqkv[idx] = f2bf(W[(size_t)o * 256 + ip] * sc);
  } else if (bid < 1024) {
    const int idx = (bid - 768) * 256 + t;
    const int op = idx >> 8, ip = idx & 255;
    const int i2 = 4 * (ip & 63) + (ip >> 6);
    wm_[idx] = f2bf(Wm[(size_t)op * 256 + i2]);
  } else if (bid < 2048) {
    const int idx = (bid - 1024) * 256 + t;
    w1_[idx] = f2bf(W1[idx]);
  } else if (bid < 2560) {
    const int idx = (bid - 2048) * 256 + t;
    w2_[idx] = f2bf(W2[idx]);
  } else {
    const int z = (bid - 2560) * 256 + t;
    if (z < 256)       biasb[z] = bq[4 * (z & 63) + (z >> 6)] * LOG2E_8;
    else if (z < 512)  { const int y = z - 256; biasb[z] = bk[4 * (y & 63) + (y >> 6)]; }
    else if (z < 768)  { const int y = z - 512; biasb[z] = bv[4 * (y & 63) + (y >> 6)]; }
    else if (z < 1024) biasb[z] = bm[z - 768];
    else if (z < 1536) biasb[z] = b1[z - 1024];
    else if (z < 1792) biasb[z] = b2[z - 1536];
  }
}

// ---------------------------------------------------------------------------
// 64(o) x BN(n)-tile MFMA GEMM, global_load_lds staging, single-buffered.
// 4 waves as 2(o) x 2(n); wave w owns o-half (w>>1)*32, n-half (w&1)*(BN/2)
// -> 32 x BN/2, 2 x (BN/32) frags. C[b,o,n] = sum_i W[o,i]*X[b,n,i] + bias.
// Grid (N/BN, Co/64, B).
// variant 0: NHC bf16 out O0; 1: fused qkv (q->O0, k->O1, v->O2 [b][h][d][n]);
// 2: CHN fp32 out O0.
// ---------------------------------------------------------------------------
template<int BN>
__global__ __launch_bounds__(256) void gemmT(
    const unsigned short* __restrict__ Wb, const float* __restrict__ bias,
    const unsigned short* __restrict__ X0, const unsigned short* __restrict__ X1,
    void* __restrict__ O0, void* __restrict__ O1, void* __restrict__ O2,
    int Co, int Ci, int Ci0, int N, int variant)
{
  constexpr int NJ = BN / 32;        // n-frags per wave (4 or 2)
  const int n0 = blockIdx.x * BN;
  const int o0 = blockIdx.y * 64;
  const int b  = blockIdx.z;
  const int t  = threadIdx.x;
  const int w = t >> 6, lane = t & 63, qd = lane >> 4, l = lane & 15;
  const int oh = (w >> 1) * 32, nh = (w & 1) * (BN / 2);

  __shared__ unsigned short Wl[64 * 64];
  __shared__ unsigned short Xl[BN * 64];

  floatx4 acc[2][NJ];
  #pragma unroll
  for (int i = 0; i < 2; ++i)
    #pragma unroll
    for (int j = 0; j < NJ; ++j) acc[i][j] = (floatx4){0.f, 0.f, 0.f, 0.f};

  for (int k0 = 0; k0 < Ci; k0 += 64) {
    const unsigned short* Xs; int cb, rl;
    if (variant == 1) { Xs = (o0 < 256) ? X0 : X1; cb = k0; rl = Ci; }
    else if (k0 < Ci0) { Xs = X0; cb = k0; rl = Ci0; }
    else               { Xs = X1; cb = k0 - Ci0; rl = Ci - Ci0; }
    __syncthreads();
    #pragma unroll
    for (int i = 0; i < 2; ++i) {
      const int idx = i * 256 + t;
      const int row = idx >> 3, pg = idx & 7, sg = pg ^ (row & 7);
      gload16(&Wb[(size_t)(o0 + row) * Ci + k0 + sg * 8], &Wl[row * 64 + pg * 8]);
    }
    #pragma unroll
    for (int i = 0; i < BN / 32; ++i) {
      const int idx = i * 256 + t;
      const int row = idx >> 3, pg = idx & 7, sg = pg ^ (row & 7);
      gload16(&Xs[((size_t)b * N + n0 + row) * rl + cb + sg * 8], &Xl[row * 64 + pg * 8]);
    }
    __syncthreads();

    short8 af[2][2], bf[NJ][2];
    #pragma unroll
    for (int i = 0; i < 2; ++i) {
      const int ar = oh + 16 * i + l;
      af[i][0] = *(const short8*)&Wl[ar * 64 + ((qd ^ (ar & 7))) * 8];
      af[i][1] = *(const short8*)&Wl[ar * 64 + (((4 + qd) ^ (ar & 7))) * 8];
    }
    #pragma unroll
    for (int j = 0; j < NJ; ++j) {
      const int br = nh + 16 * j + l;
      bf[j][0] = *(const short8*)&Xl[br * 64 + ((qd ^ (br & 7))) * 8];
      bf[j][1] = *(const short8*)&Xl[br * 64 + (((4 + qd) ^ (br & 7))) * 8];
    }
    #pragma unroll
    for (int i = 0; i < 2; ++i)
      #pragma unroll
      for (int j = 0; j < NJ; ++j) {
        acc[i][j] = __builtin_amdgcn_mfma_f32_16x16x32_bf16(af[i][0], bf[j][0], acc[i][j], 0, 0, 0);
        acc[i][j] = __builtin_amdgcn_mfma_f32_16x16x32_bf16(af[i][1], bf[j][1], acc[i][j], 0, 0, 0);
      }
  }

  const int osec = o0 + oh;
  #pragma unroll
  for (int i = 0; i < 2; ++i) {
    const int o4 = o0 + oh + 16 * i + qd * 4;
    const float4 bi = *(const float4*)&bias[o4];
    #pragma unroll
    for (int j = 0; j < NJ; ++j) {
      const int n = n0 + nh + 16 * j + l;
      if (variant == 0) {
        unsigned short* C = (unsigned short*)O0;
        ushort4 pk;
        pk.x = f2bf(acc[i][j][0] + bi.x); pk.y = f2bf(acc[i][j][1] + bi.y);
        pk.z = f2bf(acc[i][j][2] + bi.z); pk.w = f2bf(acc[i][j][3] + bi.w);
        *(ushort4*)&C[((size_t)b * N + n) * Co + o4] = pk;
      } else if (variant == 1) {
        if (osec < 256) {
          unsigned short* C = (unsigned short*)O0;
          ushort4 pk;
          pk.x = f2bf(acc[i][j][0] + bi.x); pk.y = f2bf(acc[i][j][1] + bi.y);
          pk.z = f2bf(acc[i][j][2] + bi.z); pk.w = f2bf(acc[i][j][3] + bi.w);
          *(ushort4*)&C[((size_t)b * N + n) * 256 + o4] = pk;
        } else if (osec < 512) {
          unsigned short* C = (unsigned short*)O1;
          ushort4 pk;
          pk.x = f2bf(acc[i][j][0] + bi.x); pk.y = f2bf(acc[i][j][1] + bi.y);
          pk.z = f2bf(acc[i][j][2] + bi.z); pk.w = f2bf(acc[i][j][3] + bi.w);
          *(ushort4*)&C[((size_t)b * N + n) * 256 + (o4 - 256)] = pk;
        } else {
          unsigned short* C = (unsigned short*)O2;
          #pragma unroll
          for (int rg = 0; rg < 4; ++rg) {
            const int op = o4 - 512 + rg, h = op >> 6, d = op & 63;
            C[(((size_t)b * 4 + h) * 64 + d) * N + n] =
                f2bf(acc[i][j][rg] + ((const float*)&bi)[rg]);
          }
        }
      } else {
        float* C = (float*)O0;
        #pragma unroll
        for (int rg = 0; rg < 4; ++rg)
          C[((size_t)b * Co + o4 + rg) * N + n] = acc[i][j][rg] + ((const float*)&bi)[rg];
      }
    }
  }
}

// ---------------------------------------------------------------------------
// MFMA flash attention, split-K x4, 128 q/block (r2 version, 70-72us x5).
// QK^T operand-swapped: S^T = mfma(K, Q); lane (qd,l) holds
// S^T[key = 16js + 4qd + rg][q = 16w + l]. After exp2 + cvtpk, permlane
// 32/16 swaps redistribute to the K=32 A-frag (keys 32js2 + 8qd + j).
// PV: 16 K=32 MFMAs/tile, V read as 8 conflict-free b128/tile. li on the
// MFMA pipe (ones-B-frag). K/V double-buffered in LDS, one barrier per tile,
// prefetch in flight under compute. Writes UNNORMALIZED bf16 O partial +
// fp32 li partial. Grid (N/128, H, B*4): z = b*4 + s.
// ---------------------------------------------------------------------------
__global__ __launch_bounds__(256) void attn_mfma(
    const unsigned short* __restrict__ qb, const unsigned short* __restrict__ kb,
    const unsigned short* __restrict__ vh, unsigned short* __restrict__ Opart,
    float* __restrict__ liPart, int N)
{
  const int qt = blockIdx.x;
  const int h  = blockIdx.y;
  const int b  = blockIdx.z >> 2, s = blockIdx.z & 3;
  const int n0 = qt * 128;
  const int t  = threadIdx.x;
  const int w = t >> 6, lane = t & 63, qd = lane >> 4, l = lane & 15;

  __shared__ unsigned short Kl[2][64 * 64];  // [key][d] swizzled, double-buffered
  __shared__ unsigned short Vl[2][64 * 64];  // [d][key] swizzled, double-buffered

  // Q B-frags (n = q = l) for 2 q-sets (rows 16w+l and 64+16w+l)
  const unsigned short* qp0 = &qb[((size_t)b * N + n0 + 16 * w + l) * 256 + h * 64];
  const unsigned short* qp1 = qp0 + (size_t)64 * 256;
  short8 bQ[2][2];
  bQ[0][0] = *(const short8*)&qp0[qd * 8];
  bQ[0][1] = *(const short8*)&qp0[32 + qd * 8];
  bQ[1][0] = *(const short8*)&qp1[qd * 8];
  bQ[1][1] = *(const short8*)&qp1[32 + qd * 8];

  short8 ones;
  #pragma unroll
  for (int i = 0; i < 8; ++i) ones[i] = (short)0x3F80;   // bf16 1.0

  floatx4 accO[2][4];
  floatx4 accLi[2];
  #pragma unroll
  for (int qs = 0; qs < 2; ++qs) {
    accLi[qs] = (floatx4){0.f, 0.f, 0.f, 0.f};
    #pragma unroll
    for (int ds = 0; ds < 4; ++ds) accO[qs][ds] = (floatx4){0.f, 0.f, 0.f, 0.f};
  }

  const int j0base = s * 1024;

  auto STAGE = [&](int buf, int j0) {
    #pragma unroll
    for (int i = 0; i < 2; ++i) {
      const int idx = i * 256 + t;
      const int row = idx >> 3, pg = idx & 7, sg = pg ^ (row & 7);
      gload16(&kb[((size_t)b * N + j0 + row) * 256 + h * 64 + sg * 8],
              &Kl[buf][row * 64 + pg * 8]);
      gload16(&vh[(((size_t)b * 4 + h) * 64 + row) * N + j0 + sg * 8],
              &Vl[buf][row * 64 + pg * 8]);
    }
  };

  STAGE(0, j0base);

  #pragma unroll 2
  for (int jt = 0; jt < 16; ++jt) {
    const int cur = jt & 1;
    __syncthreads();                 // buf[cur] staged; all reads of buf[cur^1] done
    if (jt < 15) STAGE(cur ^ 1, j0base + (jt + 1) * 64);  // prefetch under compute

    // ---- QK^T, both q-sets, kf transient per js ----
    floatx4 S[2][4];
    __builtin_amdgcn_s_setprio(1);
    #pragma unroll
    for (int js = 0; js < 4; ++js) {
      const int br = 16 * js + l;
      const short8 k0 = *(const short8*)&Kl[cur][br * 64 + ((qd ^ (br & 7))) * 8];
      const short8 k1 = *(const short8*)&Kl[cur][br * 64 + (((4 + qd) ^ (br & 7))) * 8];
      floatx4 a0 = (floatx4){0.f, 0.f, 0.f, 0.f};
      floatx4 a1 = (floatx4){0.f, 0.f, 0.f, 0.f};
      a0 = __builtin_amdgcn_mfma_f32_16x16x32_bf16(k0, bQ[0][0], a0, 0, 0, 0);
      a1 = __builtin_amdgcn_mfma_f32_16x16x32_bf16(k0, bQ[1][0], a1, 0, 0, 0);
      a0 = __builtin_amdgcn_mfma_f32_16x16x32_bf16(k1, bQ[0][1], a0, 0, 0, 0);
      a1 = __builtin_amdgcn_mfma_f32_16x16x32_bf16(k1, bQ[1][1], a1, 0, 0, 0);
      S[0][js] = a0; S[1][js] = a1;
    }
    __builtin_amdgcn_s_setprio(0);

    // ---- softmax + in-register K=32 A-frag assembly ----
    unsigned int T[2][2][4];   // [qs][js2][reg]
    #pragma unroll
    for (int qs = 0; qs < 2; ++qs) {
      unsigned int U[4], W[4];
      #pragma unroll
      for (int js = 0; js < 4; ++js) {
        const float p0 = __builtin_exp2f(S[qs][js][0]);
        const float p1 = __builtin_exp2f(S[qs][js][1]);
        const float p2 = __builtin_exp2f(S[qs][js][2]);
        const float p3 = __builtin_exp2f(S[qs][js][3]);
        U[js] = cvtpk(p0, p1);
        W[js] = cvtpk(p2, p3);
      }
      #pragma unroll
      for (int js2 = 0; js2 < 2; ++js2) {
        unsigned int t0 = U[2 * js2], t2 = U[2 * js2 + 1];
        asm("v_permlane32_swap_b32 %0, %1" : "+v"(t0), "+v"(t2));
        asm("v_permlane16_swap_b32 %0, %1" : "+v"(t0), "+v"(t2));
        unsigned int t1 = W[2 * js2], t3 = W[2 * js2 + 1];
        asm("v_permlane32_swap_b32 %0, %1" : "+v"(t1), "+v"(t3));
        asm("v_permlane16_swap_b32 %0, %1" : "+v"(t1), "+v"(t3));
        T[qs][js2][0] = t0; T[qs][js2][1] = t1;
        T[qs][js2][2] = t2; T[qs][js2][3] = t3;
      }
    }

    // ---- PV + li, K=32, vv transient per js2 ----
    __builtin_amdgcn_s_setprio(1);
    #pragma unroll
    for (int js2 = 0; js2 < 2; ++js2) {
      short8 vv[4];
      #pragma unroll
      for (int ds = 0; ds < 4; ++ds) {
        const int vr = 16 * ds + l;
        vv[ds] = *(const short8*)&Vl[cur][vr * 64 + (((4 * js2 + qd) ^ (vr & 7))) * 8];
      }
      #pragma unroll
      for (int qs = 0; qs < 2; ++qs) {
        U4 pu;
        pu.u[0] = T[qs][js2][0]; pu.u[1] = T[qs][js2][1];
        pu.u[2] = T[qs][js2][2]; pu.u[3] = T[qs][js2][3];
        const short8 pa = pu.s;
        #pragma unroll
        for (int ds = 0; ds < 4; ++ds)
          accO[qs][ds] = __builtin_amdgcn_mfma_f32_16x16x32_bf16(pa, vv[ds], accO[qs][ds], 0, 0, 0);
        accLi[qs] = __builtin_amdgcn_mfma_f32_16x16x32_bf16(pa, ones, accLi[qs], 0, 0, 0);
      }
    }
    __builtin_amdgcn_s_setprio(0);
  }

  // epilogue: unnormalized partials. accO row = q = qs*64 + 16w + 4qd + rg.
  const size_t obase = ((((size_t)b * 4 + h) * 4 + s) * 32 + qt) * 128;
  #pragma unroll
  for (int qs = 0; qs < 2; ++qs)
    #pragma unroll
    for (int rg = 0; rg < 4; ++rg) {
      const int q = qs * 64 + 16 * w + qd * 4 + rg;
      #pragma unroll
      for (int ds = 0; ds < 4; ++ds)
        Opart[(obase + q) * 64 + 16 * ds + l] = f2bf(accO[qs][ds][rg]);
      if (l == 0) liPart[obase + q] = accLi[qs][rg];
    }
}

// ---------------------------------------------------------------------------
// Combine 4 split-K partials -> atb NHC head-major bf16. Grid (N/128, H, B).
// ---------------------------------------------------------------------------
__global__ __launch_bounds__(256) void attn_combine(
    const unsigned short* __restrict__ Opart, const float* __restrict__ liPart,
    unsigned short* __restrict__ atb, int N)
{
  const int qt = blockIdx.x, h = blockIdx.y, b = blockIdx.z;
  const int t = threadIdx.x;
  const int q = t >> 1, d0 = (t & 1) * 32;

  float li = 0.f;
  size_t idx[4];
  #pragma unroll
  for (int s = 0; s < 4; ++s) {
    idx[s] = ((((size_t)b * 4 + h) * 4 + s) * 32 + qt) * 128 + q;
    li += liPart[idx[s]];
  }
  const float inv = 1.f / li;

  float o[32];
  #pragma unroll
  for (int c = 0; c < 32; ++c) o[c] = 0.f;
  #pragma unroll
  for (int s = 0; s < 4; ++s) {
    #pragma unroll
    for (int c4 = 0; c4 < 4; ++c4) {
      const short8 v = *(const short8*)&Opart[idx[s] * 64 + d0 + c4 * 8];
      #pragma unroll
      for (int j = 0; j < 8; ++j) o[c4 * 8 + j] += bf2f((unsigned short)v[j]);
    }
  }
  unsigned short* dst = &atb[((size_t)b * N + qt * 128 + q) * 256 + h * 64 + d0];
  #pragma unroll
  for (int c4 = 0; c4 < 4; ++c4) {
    ushort4 pk;
    pk.x = f2bf(o[c4 * 8 + 0] * inv); pk.y = f2bf(o[c4 * 8 + 1] * inv);
    pk.z = f2bf(o[c4 * 8 + 2] * inv); pk.w = f2bf(o[c4 * 8 + 3] * inv);
    *(ushort4*)&dst[c4 * 8] = pk;
    pk.x = f2bf(o[c4 * 8 + 4] * inv); pk.y = f2bf(o[c4 * 8 + 5] * inv);
    pk.z = f2bf(o[c4 * 8 + 6] * inv); pk.w = f2bf(o[c4 * 8 + 7] * inv);
    *(ushort4*)&dst[c4 * 8 + 4] = pk;
  }
}

// ---------------------------------------------------------------------------
// InstanceNorm on NHC h [b][n][512]: partial sums, then fused final+normalize.
// ---------------------------------------------------------------------------
__global__ __launch_bounds__(256) void in_stats(
    const unsigned short* __restrict__ H, float* __restrict__ Ps,
    float* __restrict__ Ps2, int N)
{
  const int cg = blockIdx.x, ns = blockIdx.y, b = blockIdx.z, t = threadIdx.x;
  const int c0 = cg * 64 + (t & 7) * 8;
  float s[8] = {}, s2[8] = {};
  #pragma unroll
  for (int i = 0; i < 8; ++i) {
    const int n = ns * 256 + (t >> 3) + i * 32;
    const short8 hv = *(const short8*)&H[((size_t)b * N + n) * 512 + c0];
    #pragma unroll
    for (int j = 0; j < 8; ++j) {
      const float f = bf2f((unsigned short)hv[j]);
      s[j] += f; s2[j] += f * f;
    }
  }
  __shared__ float rs[32][64], rs2[32][64];
  #pragma unroll
  for (int j = 0; j < 8; ++j) {
    rs[t >> 3][(t & 7) * 8 + j] = s[j];
    rs2[t >> 3][(t & 7) * 8 + j] = s2[j];
  }
  __syncthreads();
  if (t < 64) {
    float a = 0.f, a2 = 0.f;
    #pragma unroll
    for (int r = 0; r < 32; ++r) { a += rs[r][t]; a2 += rs2[r][t]; }
    const size_t o = ((size_t)ns * 2 + b) * 512 + cg * 64 + t;
    Ps[o] = a; Ps2[o] = a2;
  }
}

__global__ __launch_bounds__(256) void in_norm(
    unsigned short* __restrict__ H, const float* __restrict__ Ps,
    const float* __restrict__ Ps2, int N)
{
  const int cg = blockIdx.x, ns = blockIdx.y, b = blockIdx.z, t = threadIdx.x;
  __shared__ float muS[64], ivS[64];
  if (t < 64) {
    const int c = cg * 64 + t;
    float s = 0.f, s2 = 0.f;
    for (int k = 0; k < 16; ++k) {
      s  += Ps [((size_t)k * 2 + b) * 512 + c];
      s2 += Ps2[((size_t)k * 2 + b) * 512 + c];
    }
    const float mu = s / (float)N;
    const float var = fmaxf(s2 / (float)N - mu * mu, 0.f);
    muS[t] = mu;
    ivS[t] = rsqrtf(var + 1e-5f);
  }
  __syncthreads();
  const int c0 = cg * 64 + (t & 7) * 8;
  float mu[8], iv[8];
  #pragma unroll
  for (int j = 0; j < 8; ++j) {
    mu[j] = muS[(t & 7) * 8 + j];
    iv[j] = ivS[(t & 7) * 8 + j];
  }
  #pragma unroll
  for (int i = 0; i < 8; ++i) {
    const int n = ns * 256 + (t >> 3) + i * 32;
    unsigned short* p = &H[((size_t)b * N + n) * 512 + c0];
    short8 hv = *(const short8*)p;
    #pragma unroll
    for (int j = 0; j < 8; ++j) {
      const float f = fmaxf((bf2f((unsigned short)hv[j]) - mu[j]) * iv[j], 0.f);
      hv[j] = (short)f2bf(f);
    }
    *(short8*)p = hv;
  }
}

// ---------------------------------------------------------------------------
extern "C" void kernel_launch(void* const* d_in, const int* in_sizes, int n_in,
                              void* d_out, int out_size, void* d_ws, size_t ws_size,
                              hipStream_t stream)
{
  const int B = 2, D = 256, N = 4096;

  const float* x   = (const float*)d_in[0];
  const float* src = (const float*)d_in[1];
  const float* Wq  = (const float*)d_in[2];  const float* bq = (const float*)d_in[3];
  const float* Wk  = (const float*)d_in[4];  const float* bk = (const float*)d_in[5];
  const float* Wv  = (const float*)d_in[6];  const float* bv = (const float*)d_in[7];
  const float* Wm  = (const float*)d_in[8];  const float* bm = (const float*)d_in[9];
  const float* W1  = (const float*)d_in[10]; const float* b1 = (const float*)d_in[11];
  const float* W2  = (const float*)d_in[12]; const float* b2 = (const float*)d_in[13];
  float* out = (float*)d_out;

  char* ws = (char*)d_ws;
  const size_t MB = 1u << 20;
  unsigned short* xb  = (unsigned short*)(ws + 0 * MB);    // [b][n][256] bf16
  unsigned short* sb  = (unsigned short*)(ws + 4 * MB);
  unsigned short* qbf = (unsigned short*)(ws + 8 * MB);    // head-major NHC
  unsigned short* kbf = (unsigned short*)(ws + 12 * MB);
  unsigned short* vhb = (unsigned short*)(ws + 16 * MB);   // [b][h][d][n]
  unsigned short* atb = (unsigned short*)(ws + 20 * MB);   // head-major NHC
  // Opart (24..41 MB) temporally overlaps msb/hb (dead during attention)
  unsigned short* Opart = (unsigned short*)(ws + 24 * MB); // 16.78 MB bf16
  unsigned short* msb = (unsigned short*)(ws + 24 * MB);   // NHC 256 (post-combine)
  unsigned short* hb  = (unsigned short*)(ws + 28 * MB);   // [b][n][512]
  float* liPart = (float*)(ws + 41 * MB);                  // 524 KB
  unsigned short* wqkvb = (unsigned short*)(ws + 42 * MB); // [768][256]
  unsigned short* wmb = wqkvb + 768 * 256;
  unsigned short* w1b = wmb + 256 * 256;                   // [512][512]
  unsigned short* w2b = w1b + 512 * 512;                   // [256][512]
  float* biasb = (float*)(ws + 44 * MB);                   // 1792 floats
  float* Ps    = biasb + 2048;                             // 16384 floats
  float* Ps2   = Ps + 16 * 2 * 512;

  const dim3 blk(256);

  tx_all<<<dim3(N / 32, D / 32, 2 * B), blk, 0, stream>>>(x, src, xb, sb, D, N);
  wprep<<<dim3(2567), blk, 0, stream>>>(Wq, Wk, Wv, Wm, W1, W2,
                                        bq, bk, bv, bm, b1, b2,
                                        wqkvb, wmb, w1b, w2b, biasb);

  // fused q/k/v: Co=768, o<256 reads xb (q), else sb (k,v)  [BN=128, 3/CU]
  gemmT<128><<<dim3(N / 128, 12, B), blk, 0, stream>>>(
      wqkvb, biasb, xb, sb, qbf, kbf, vhb, 768, 256, 256, N, 1);

  attn_mfma<<<dim3(N / 128, 4, B * 4), blk, 0, stream>>>(
      qbf, kbf, vhb, Opart, liPart, N);
  attn_combine<<<dim3(N / 128, 4, B), blk, 0, stream>>>(Opart, liPart, atb, N);

  // message (cols head-major-permuted to match atb)  [BN=64: 512 blocks]
  gemmT<64><<<dim3(N / 64, 4, B), blk, 0, stream>>>(
      wmb, biasb + 768, atb, atb, msb, nullptr, nullptr, 256, 256, 256, N, 0);

  // h = W1 @ [x; msg]  [BN=64: 1024 blocks]
  gemmT<64><<<dim3(N / 64, 8, B), blk, 0, stream>>>(
      w1b, biasb + 1024, xb, msb, hb, nullptr, nullptr, 512, 512, 256, N, 0);

  in_stats<<<dim3(8, 16, B), blk, 0, stream>>>(hb, Ps, Ps2, N);
  in_norm<<<dim3(8, 16, B), blk, 0, stream>>>(hb, Ps, Ps2, N);

  // out = W2 @ h (fp32 CHN)  [BN=64: 512 blocks]
  gemmT<64><<<dim3(N / 64, 4, B), blk, 0, stream>>>(
      w2b, biasb + 1536, hb, hb, out, nullptr, nullptr, 256, 512, 512, N, 2);
}

// Round 10
// 208.157 us; speedup vs baseline: 1.0146x; 1.0146x over previous
//
#include <hip/hip_runtime.h>
#include <cstdint>
#include <cstddef>

// fp32 I/O. Internals: bf16 NHC activations + MFMA everywhere.
// mfma_f32_16x16x32_bf16 layouts (HW-verified m89/m120):
//   A: m=lane&15, k=quad*8+j   B: n=lane&15, k=quad*8+j
//   C/D: col(n)=lane&15, row(m)=quad*4+reg
// LDS tiles [row][64] bf16, XOR swizzle applied to the GLOBAL source chunk
// (sg = pg ^ (row&7)) so global_load_lds produces the swizzled image
// (involutive); frag reads conflict-free.
// Softmax: fixed-shift exp2, log2(e)/8 folded into Wq/bq. Split-K additive.
// r2 (220.2us): PV via K=32 MFMA (permlane32/16 P redistribution); li on
// MFMA pipe (ones-B-frag); attn K/V double-buffered, 1 barrier/tile.
// r7/r8 (208.9us, MEASURED WIN +11.3): gemm o-tile 128->64 doubled every
// gemm grid -> 1-3 blocks/CU of latency hiding. attn unchanged 71.8us.
// r9: n-tile 128->64 for the three variant-0/2 gemms (msg 512 blocks, h
// 1024, W2 512; LDS 16KB). Result AMBIGUOUS: total 211.2 but attn (code-
// identical, runs before any change) was 78.6 vs 70-72 in all 15 prior
// samples with proportionally lower hbm_gbps -> slow-clock acquire; the
// changed rest-time IMPROVED 137.1->132.6.
// r10: EXACT RESUBMIT of r9 to disambiguate (pre-committed rule: attn back
// to ~72 -> keep BN=64; attn >=78 again -> revert to r8 next round).

typedef __attribute__((ext_vector_type(8))) short short8;
typedef __attribute__((ext_vector_type(4))) float floatx4;

union U4 { unsigned int u[4]; short8 s; };

__device__ __forceinline__ unsigned short f2bf(float x) {
  union { float f; unsigned int u; } c; c.f = x;
  unsigned int r = c.u + 0x7FFFu + ((c.u >> 16) & 1u);   // RNE
  return (unsigned short)(r >> 16);
}
__device__ __forceinline__ float bf2f(unsigned short u) {
  union { unsigned int i; float f; } c; c.i = ((unsigned int)u) << 16; return c.f;
}
__device__ __forceinline__ void gload16(const void* g, void* l) {
  __builtin_amdgcn_global_load_lds(
      (const __attribute__((address_space(1))) unsigned int*)g,
      (__attribute__((address_space(3))) unsigned int*)l, 16, 0, 0);
}
// packed f32x2 -> bf16x2 (RNE), lo = s0, hi = s1
__device__ __forceinline__ unsigned int cvtpk(float lo, float hi) {
  unsigned int r;
  asm("v_cvt_pk_bf16_f32 %0, %1, %2" : "=v"(r) : "v"(lo), "v"(hi));
  return r;
}

#define LOG2E_8 0.18033688011112042f

// ---------------------------------------------------------------------------
// Transpose+convert both inputs: [b][c][n] fp32 -> [b][n][c] bf16.
// Grid (N/32, C/32, 2*B): z = which*2 + b.
// ---------------------------------------------------------------------------
__global__ __launch_bounds__(256) void tx_all(
    const float* __restrict__ x, const float* __restrict__ src,
    unsigned short* __restrict__ xb, unsigned short* __restrict__ sb,
    int C, int N)
{
  __shared__ float tile[32][33];
  const int which = blockIdx.z >> 1, b = blockIdx.z & 1;
  const float* X = which ? src : x;
  unsigned short* Y = which ? sb : xb;
  const int n0 = blockIdx.x * 32, c0 = blockIdx.y * 32;
  const int tc = threadIdx.x & 31, tr = threadIdx.x >> 5;
  #pragma unroll
  for (int i = 0; i < 4; ++i)
    tile[tr + i * 8][tc] = X[((size_t)b * C + c0 + tr + i * 8) * N + n0 + tc];
  __syncthreads();
  #pragma unroll
  for (int i = 0; i < 4; ++i)
    Y[((size_t)b * N + n0 + tr + i * 8) * C + c0 + tc] = f2bf(tile[tc][tr + i * 8]);
}

// ---------------------------------------------------------------------------
// All weight+bias converts in ONE dispatch. Grid 2567 blocks.
// wqkv rows head-major (o' = h*64+d reads o = 4*d+h); Wq/bq scaled log2e/8;
// Wm columns head-major.
// ---------------------------------------------------------------------------
__global__ __launch_bounds__(256) void wprep(
    const float* __restrict__ Wq, const float* __restrict__ Wk,
    const float* __restrict__ Wv, const float* __restrict__ Wm,
    const float* __restrict__ W1, const float* __restrict__ W2,
    const float* __restrict__ bq, const float* __restrict__ bk,
    const float* __restrict__ bv, const float* __restrict__ bm,
    const float* __restrict__ b1, const float* __restrict__ b2,
    unsigned short* __restrict__ wqkv, unsigned short* __restrict__ wm_,
    unsigned short* __restrict__ w1_, unsigned short* __restrict__ w2_,
    float* __restrict__ biasb)
{
  const int bid = blockIdx.x, t = threadIdx.x;
  if (bid < 768) {
    const int idx = bid * 256 + t;
    const int op = idx >> 8, ip = idx & 255;
    const int grp = op >> 8, oo = op & 255;
    const int o = 4 * (oo & 63) + (oo >> 6);
    const float* W = grp == 0 ? Wq : grp == 1 ? Wk : Wv;
    const float sc = grp == 0 ? LOG2E_8 : 1.f;
    wqkv[idx] = f2bf(W[(size_t)o * 256 + ip] * sc);
  } else if (bid < 1024) {
    const int idx = (bid - 768) * 256 + t;
    const int op = idx >> 8, ip = idx & 255;
    const int i2 = 4 * (ip & 63) + (ip >> 6);
    wm_[idx] = f2bf(Wm[(size_t)op * 256 + i2]);
  } else if (bid < 2048) {
    const int idx = (bid - 1024) * 256 + t;
    w1_[idx] = f2bf(W1[idx]);
  } else if (bid < 2560) {
    const int idx = (bid - 2048) * 256 + t;
    w2_[idx] = f2bf(W2[idx]);
  } else {
    const int z = (bid - 2560) * 256 + t;
    if (z < 256)       biasb[z] = bq[4 * (z & 63) + (z >> 6)] * LOG2E_8;
    else if (z < 512)  { const int y = z - 256; biasb[z] = bk[4 * (y & 63) + (y >> 6)]; }
    else if (z < 768)  { const int y = z - 512; biasb[z] = bv[4 * (y & 63) + (y >> 6)]; }
    else if (z < 1024) biasb[z] = bm[z - 768];
    else if (z < 1536) biasb[z] = b1[z - 1024];
    else if (z < 1792) biasb[z] = b2[z - 1536];
  }
}

// ---------------------------------------------------------------------------
// 64(o) x BN(n)-tile MFMA GEMM, global_load_lds staging, single-buffered.
// 4 waves as 2(o) x 2(n); wave w owns o-half (w>>1)*32, n-half (w&1)*(BN/2)
// -> 32 x BN/2, 2 x (BN/32) frags. C[b,o,n] = sum_i W[o,i]*X[b,n,i] + bias.
// Grid (N/BN, Co/64, B).
// variant 0: NHC bf16 out O0; 1: fused qkv (q->O0, k->O1, v->O2 [b][h][d][n]);
// 2: CHN fp32 out O0.
// ---------------------------------------------------------------------------
template<int BN>
__global__ __launch_bounds__(256) void gemmT(
    const unsigned short* __restrict__ Wb, const float* __restrict__ bias,
    const unsigned short* __restrict__ X0, const unsigned short* __restrict__ X1,
    void* __restrict__ O0, void* __restrict__ O1, void* __restrict__ O2,
    int Co, int Ci, int Ci0, int N, int variant)
{
  constexpr int NJ = BN / 32;        // n-frags per wave (4 or 2)
  const int n0 = blockIdx.x * BN;
  const int o0 = blockIdx.y * 64;
  const int b  = blockIdx.z;
  const int t  = threadIdx.x;
  const int w = t >> 6, lane = t & 63, qd = lane >> 4, l = lane & 15;
  const int oh = (w >> 1) * 32, nh = (w & 1) * (BN / 2);

  __shared__ unsigned short Wl[64 * 64];
  __shared__ unsigned short Xl[BN * 64];

  floatx4 acc[2][NJ];
  #pragma unroll
  for (int i = 0; i < 2; ++i)
    #pragma unroll
    for (int j = 0; j < NJ; ++j) acc[i][j] = (floatx4){0.f, 0.f, 0.f, 0.f};

  for (int k0 = 0; k0 < Ci; k0 += 64) {
    const unsigned short* Xs; int cb, rl;
    if (variant == 1) { Xs = (o0 < 256) ? X0 : X1; cb = k0; rl = Ci; }
    else if (k0 < Ci0) { Xs = X0; cb = k0; rl = Ci0; }
    else               { Xs = X1; cb = k0 - Ci0; rl = Ci - Ci0; }
    __syncthreads();
    #pragma unroll
    for (int i = 0; i < 2; ++i) {
      const int idx = i * 256 + t;
      const int row = idx >> 3, pg = idx & 7, sg = pg ^ (row & 7);
      gload16(&Wb[(size_t)(o0 + row) * Ci + k0 + sg * 8], &Wl[row * 64 + pg * 8]);
    }
    #pragma unroll
    for (int i = 0; i < BN / 32; ++i) {
      const int idx = i * 256 + t;
      const int row = idx >> 3, pg = idx & 7, sg = pg ^ (row & 7);
      gload16(&Xs[((size_t)b * N + n0 + row) * rl + cb + sg * 8], &Xl[row * 64 + pg * 8]);
    }
    __syncthreads();

    short8 af[2][2], bf[NJ][2];
    #pragma unroll
    for (int i = 0; i < 2; ++i) {
      const int ar = oh + 16 * i + l;
      af[i][0] = *(const short8*)&Wl[ar * 64 + ((qd ^ (ar & 7))) * 8];
      af[i][1] = *(const short8*)&Wl[ar * 64 + (((4 + qd) ^ (ar & 7))) * 8];
    }
    #pragma unroll
    for (int j = 0; j < NJ; ++j) {
      const int br = nh + 16 * j + l;
      bf[j][0] = *(const short8*)&Xl[br * 64 + ((qd ^ (br & 7))) * 8];
      bf[j][1] = *(const short8*)&Xl[br * 64 + (((4 + qd) ^ (br & 7))) * 8];
    }
    #pragma unroll
    for (int i = 0; i < 2; ++i)
      #pragma unroll
      for (int j = 0; j < NJ; ++j) {
        acc[i][j] = __builtin_amdgcn_mfma_f32_16x16x32_bf16(af[i][0], bf[j][0], acc[i][j], 0, 0, 0);
        acc[i][j] = __builtin_amdgcn_mfma_f32_16x16x32_bf16(af[i][1], bf[j][1], acc[i][j], 0, 0, 0);
      }
  }

  const int osec = o0 + oh;
  #pragma unroll
  for (int i = 0; i < 2; ++i) {
    const int o4 = o0 + oh + 16 * i + qd * 4;
    const float4 bi = *(const float4*)&bias[o4];
    #pragma unroll
    for (int j = 0; j < NJ; ++j) {
      const int n = n0 + nh + 16 * j + l;
      if (variant == 0) {
        unsigned short* C = (unsigned short*)O0;
        ushort4 pk;
        pk.x = f2bf(acc[i][j][0] + bi.x); pk.y = f2bf(acc[i][j][1] + bi.y);
        pk.z = f2bf(acc[i][j][2] + bi.z); pk.w = f2bf(acc[i][j][3] + bi.w);
        *(ushort4*)&C[((size_t)b * N + n) * Co + o4] = pk;
      } else if (variant == 1) {
        if (osec < 256) {
          unsigned short* C = (unsigned short*)O0;
          ushort4 pk;
          pk.x = f2bf(acc[i][j][0] + bi.x); pk.y = f2bf(acc[i][j][1] + bi.y);
          pk.z = f2bf(acc[i][j][2] + bi.z); pk.w = f2bf(acc[i][j][3] + bi.w);
          *(ushort4*)&C[((size_t)b * N + n) * 256 + o4] = pk;
        } else if (osec < 512) {
          unsigned short* C = (unsigned short*)O1;
          ushort4 pk;
          pk.x = f2bf(acc[i][j][0] + bi.x); pk.y = f2bf(acc[i][j][1] + bi.y);
          pk.z = f2bf(acc[i][j][2] + bi.z); pk.w = f2bf(acc[i][j][3] + bi.w);
          *(ushort4*)&C[((size_t)b * N + n) * 256 + (o4 - 256)] = pk;
        } else {
          unsigned short* C = (unsigned short*)O2;
          #pragma unroll
          for (int rg = 0; rg < 4; ++rg) {
            const int op = o4 - 512 + rg, h = op >> 6, d = op & 63;
            C[(((size_t)b * 4 + h) * 64 + d) * N + n] =
                f2bf(acc[i][j][rg] + ((const float*)&bi)[rg]);
          }
        }
      } else {
        float* C = (float*)O0;
        #pragma unroll
        for (int rg = 0; rg < 4; ++rg)
          C[((size_t)b * Co + o4 + rg) * N + n] = acc[i][j][rg] + ((const float*)&bi)[rg];
      }
    }
  }
}

// ---------------------------------------------------------------------------
// MFMA flash attention, split-K x4, 128 q/block (r2 version, 70-72us x15).
// QK^T operand-swapped: S^T = mfma(K, Q); lane (qd,l) holds
// S^T[key = 16js + 4qd + rg][q = 16w + l]. After exp2 + cvtpk, permlane
// 32/16 swaps redistribute to the K=32 A-frag (keys 32js2 + 8qd + j).
// PV: 16 K=32 MFMAs/tile, V read as 8 conflict-free b128/tile. li on the
// MFMA pipe (ones-B-frag). K/V double-buffered in LDS, one barrier per tile,
// prefetch in flight under compute. Writes UNNORMALIZED bf16 O partial +
// fp32 li partial. Grid (N/128, H, B*4): z = b*4 + s.
// ---------------------------------------------------------------------------
__global__ __launch_bounds__(256) void attn_mfma(
    const unsigned short* __restrict__ qb, const unsigned short* __restrict__ kb,
    const unsigned short* __restrict__ vh, unsigned short* __restrict__ Opart,
    float* __restrict__ liPart, int N)
{
  const int qt = blockIdx.x;
  const int h  = blockIdx.y;
  const int b  = blockIdx.z >> 2, s = blockIdx.z & 3;
  const int n0 = qt * 128;
  const int t  = threadIdx.x;
  const int w = t >> 6, lane = t & 63, qd = lane >> 4, l = lane & 15;

  __shared__ unsigned short Kl[2][64 * 64];  // [key][d] swizzled, double-buffered
  __shared__ unsigned short Vl[2][64 * 64];  // [d][key] swizzled, double-buffered

  // Q B-frags (n = q = l) for 2 q-sets (rows 16w+l and 64+16w+l)
  const unsigned short* qp0 = &qb[((size_t)b * N + n0 + 16 * w + l) * 256 + h * 64];
  const unsigned short* qp1 = qp0 + (size_t)64 * 256;
  short8 bQ[2][2];
  bQ[0][0] = *(const short8*)&qp0[qd * 8];
  bQ[0][1] = *(const short8*)&qp0[32 + qd * 8];
  bQ[1][0] = *(const short8*)&qp1[qd * 8];
  bQ[1][1] = *(const short8*)&qp1[32 + qd * 8];

  short8 ones;
  #pragma unroll
  for (int i = 0; i < 8; ++i) ones[i] = (short)0x3F80;   // bf16 1.0

  floatx4 accO[2][4];
  floatx4 accLi[2];
  #pragma unroll
  for (int qs = 0; qs < 2; ++qs) {
    accLi[qs] = (floatx4){0.f, 0.f, 0.f, 0.f};
    #pragma unroll
    for (int ds = 0; ds < 4; ++ds) accO[qs][ds] = (floatx4){0.f, 0.f, 0.f, 0.f};
  }

  const int j0base = s * 1024;

  auto STAGE = [&](int buf, int j0) {
    #pragma unroll
    for (int i = 0; i < 2; ++i) {
      const int idx = i * 256 + t;
      const int row = idx >> 3, pg = idx & 7, sg = pg ^ (row & 7);
      gload16(&kb[((size_t)b * N + j0 + row) * 256 + h * 64 + sg * 8],
              &Kl[buf][row * 64 + pg * 8]);
      gload16(&vh[(((size_t)b * 4 + h) * 64 + row) * N + j0 + sg * 8],
              &Vl[buf][row * 64 + pg * 8]);
    }
  };

  STAGE(0, j0base);

  #pragma unroll 2
  for (int jt = 0; jt < 16; ++jt) {
    const int cur = jt & 1;
    __syncthreads();                 // buf[cur] staged; all reads of buf[cur^1] done
    if (jt < 15) STAGE(cur ^ 1, j0base + (jt + 1) * 64);  // prefetch under compute

    // ---- QK^T, both q-sets, kf transient per js ----
    floatx4 S[2][4];
    __builtin_amdgcn_s_setprio(1);
    #pragma unroll
    for (int js = 0; js < 4; ++js) {
      const int br = 16 * js + l;
      const short8 k0 = *(const short8*)&Kl[cur][br * 64 + ((qd ^ (br & 7))) * 8];
      const short8 k1 = *(const short8*)&Kl[cur][br * 64 + (((4 + qd) ^ (br & 7))) * 8];
      floatx4 a0 = (floatx4){0.f, 0.f, 0.f, 0.f};
      floatx4 a1 = (floatx4){0.f, 0.f, 0.f, 0.f};
      a0 = __builtin_amdgcn_mfma_f32_16x16x32_bf16(k0, bQ[0][0], a0, 0, 0, 0);
      a1 = __builtin_amdgcn_mfma_f32_16x16x32_bf16(k0, bQ[1][0], a1, 0, 0, 0);
      a0 = __builtin_amdgcn_mfma_f32_16x16x32_bf16(k1, bQ[0][1], a0, 0, 0, 0);
      a1 = __builtin_amdgcn_mfma_f32_16x16x32_bf16(k1, bQ[1][1], a1, 0, 0, 0);
      S[0][js] = a0; S[1][js] = a1;
    }
    __builtin_amdgcn_s_setprio(0);

    // ---- softmax + in-register K=32 A-frag assembly ----
    unsigned int T[2][2][4];   // [qs][js2][reg]
    #pragma unroll
    for (int qs = 0; qs < 2; ++qs) {
      unsigned int U[4], W[4];
      #pragma unroll
      for (int js = 0; js < 4; ++js) {
        const float p0 = __builtin_exp2f(S[qs][js][0]);
        const float p1 = __builtin_exp2f(S[qs][js][1]);
        const float p2 = __builtin_exp2f(S[qs][js][2]);
        const float p3 = __builtin_exp2f(S[qs][js][3]);
        U[js] = cvtpk(p0, p1);
        W[js] = cvtpk(p2, p3);
      }
      #pragma unroll
      for (int js2 = 0; js2 < 2; ++js2) {
        unsigned int t0 = U[2 * js2], t2 = U[2 * js2 + 1];
        asm("v_permlane32_swap_b32 %0, %1" : "+v"(t0), "+v"(t2));
        asm("v_permlane16_swap_b32 %0, %1" : "+v"(t0), "+v"(t2));
        unsigned int t1 = W[2 * js2], t3 = W[2 * js2 + 1];
        asm("v_permlane32_swap_b32 %0, %1" : "+v"(t1), "+v"(t3));
        asm("v_permlane16_swap_b32 %0, %1" : "+v"(t1), "+v"(t3));
        T[qs][js2][0] = t0; T[qs][js2][1] = t1;
        T[qs][js2][2] = t2; T[qs][js2][3] = t3;
      }
    }

    // ---- PV + li, K=32, vv transient per js2 ----
    __builtin_amdgcn_s_setprio(1);
    #pragma unroll
    for (int js2 = 0; js2 < 2; ++js2) {
      short8 vv[4];
      #pragma unroll
      for (int ds = 0; ds < 4; ++ds) {
        const int vr = 16 * ds + l;
        vv[ds] = *(const short8*)&Vl[cur][vr * 64 + (((4 * js2 + qd) ^ (vr & 7))) * 8];
      }
      #pragma unroll
      for (int qs = 0; qs < 2; ++qs) {
        U4 pu;
        pu.u[0] = T[qs][js2][0]; pu.u[1] = T[qs][js2][1];
        pu.u[2] = T[qs][js2][2]; pu.u[3] = T[qs][js2][3];
        const short8 pa = pu.s;
        #pragma unroll
        for (int ds = 0; ds < 4; ++ds)
          accO[qs][ds] = __builtin_amdgcn_mfma_f32_16x16x32_bf16(pa, vv[ds], accO[qs][ds], 0, 0, 0);
        accLi[qs] = __builtin_amdgcn_mfma_f32_16x16x32_bf16(pa, ones, accLi[qs], 0, 0, 0);
      }
    }
    __builtin_amdgcn_s_setprio(0);
  }

  // epilogue: unnormalized partials. accO row = q = qs*64 + 16w + 4qd + rg.
  const size_t obase = ((((size_t)b * 4 + h) * 4 + s) * 32 + qt) * 128;
  #pragma unroll
  for (int qs = 0; qs < 2; ++qs)
    #pragma unroll
    for (int rg = 0; rg < 4; ++rg) {
      const int q = qs * 64 + 16 * w + qd * 4 + rg;
      #pragma unroll
      for (int ds = 0; ds < 4; ++ds)
        Opart[(obase + q) * 64 + 16 * ds + l] = f2bf(accO[qs][ds][rg]);
      if (l == 0) liPart[obase + q] = accLi[qs][rg];
    }
}

// ---------------------------------------------------------------------------
// Combine 4 split-K partials -> atb NHC head-major bf16. Grid (N/128, H, B).
// ---------------------------------------------------------------------------
__global__ __launch_bounds__(256) void attn_combine(
    const unsigned short* __restrict__ Opart, const float* __restrict__ liPart,
    unsigned short* __restrict__ atb, int N)
{
  const int qt = blockIdx.x, h = blockIdx.y, b = blockIdx.z;
  const int t = threadIdx.x;
  const int q = t >> 1, d0 = (t & 1) * 32;

  float li = 0.f;
  size_t idx[4];
  #pragma unroll
  for (int s = 0; s < 4; ++s) {
    idx[s] = ((((size_t)b * 4 + h) * 4 + s) * 32 + qt) * 128 + q;
    li += liPart[idx[s]];
  }
  const float inv = 1.f / li;

  float o[32];
  #pragma unroll
  for (int c = 0; c < 32; ++c) o[c] = 0.f;
  #pragma unroll
  for (int s = 0; s < 4; ++s) {
    #pragma unroll
    for (int c4 = 0; c4 < 4; ++c4) {
      const short8 v = *(const short8*)&Opart[idx[s] * 64 + d0 + c4 * 8];
      #pragma unroll
      for (int j = 0; j < 8; ++j) o[c4 * 8 + j] += bf2f((unsigned short)v[j]);
    }
  }
  unsigned short* dst = &atb[((size_t)b * N + qt * 128 + q) * 256 + h * 64 + d0];
  #pragma unroll
  for (int c4 = 0; c4 < 4; ++c4) {
    ushort4 pk;
    pk.x = f2bf(o[c4 * 8 + 0] * inv); pk.y = f2bf(o[c4 * 8 + 1] * inv);
    pk.z = f2bf(o[c4 * 8 + 2] * inv); pk.w = f2bf(o[c4 * 8 + 3] * inv);
    *(ushort4*)&dst[c4 * 8] = pk;
    pk.x = f2bf(o[c4 * 8 + 4] * inv); pk.y = f2bf(o[c4 * 8 + 5] * inv);
    pk.z = f2bf(o[c4 * 8 + 6] * inv); pk.w = f2bf(o[c4 * 8 + 7] * inv);
    *(ushort4*)&dst[c4 * 8 + 4] = pk;
  }
}

// ---------------------------------------------------------------------------
// InstanceNorm on NHC h [b][n][512]: partial sums, then fused final+normalize.
// ---------------------------------------------------------------------------
__global__ __launch_bounds__(256) void in_stats(
    const unsigned short* __restrict__ H, float* __restrict__ Ps,
    float* __restrict__ Ps2, int N)
{
  const int cg = blockIdx.x, ns = blockIdx.y, b = blockIdx.z, t = threadIdx.x;
  const int c0 = cg * 64 + (t & 7) * 8;
  float s[8] = {}, s2[8] = {};
  #pragma unroll
  for (int i = 0; i < 8; ++i) {
    const int n = ns * 256 + (t >> 3) + i * 32;
    const short8 hv = *(const short8*)&H[((size_t)b * N + n) * 512 + c0];
    #pragma unroll
    for (int j = 0; j < 8; ++j) {
      const float f = bf2f((unsigned short)hv[j]);
      s[j] += f; s2[j] += f * f;
    }
  }
  __shared__ float rs[32][64], rs2[32][64];
  #pragma unroll
  for (int j = 0; j < 8; ++j) {
    rs[t >> 3][(t & 7) * 8 + j] = s[j];
    rs2[t >> 3][(t & 7) * 8 + j] = s2[j];
  }
  __syncthreads();
  if (t < 64) {
    float a = 0.f, a2 = 0.f;
    #pragma unroll
    for (int r = 0; r < 32; ++r) { a += rs[r][t]; a2 += rs2[r][t]; }
    const size_t o = ((size_t)ns * 2 + b) * 512 + cg * 64 + t;
    Ps[o] = a; Ps2[o] = a2;
  }
}

__global__ __launch_bounds__(256) void in_norm(
    unsigned short* __restrict__ H, const float* __restrict__ Ps,
    const float* __restrict__ Ps2, int N)
{
  const int cg = blockIdx.x, ns = blockIdx.y, b = blockIdx.z, t = threadIdx.x;
  __shared__ float muS[64], ivS[64];
  if (t < 64) {
    const int c = cg * 64 + t;
    float s = 0.f, s2 = 0.f;
    for (int k = 0; k < 16; ++k) {
      s  += Ps [((size_t)k * 2 + b) * 512 + c];
      s2 += Ps2[((size_t)k * 2 + b) * 512 + c];
    }
    const float mu = s / (float)N;
    const float var = fmaxf(s2 / (float)N - mu * mu, 0.f);
    muS[t] = mu;
    ivS[t] = rsqrtf(var + 1e-5f);
  }
  __syncthreads();
  const int c0 = cg * 64 + (t & 7) * 8;
  float mu[8], iv[8];
  #pragma unroll
  for (int j = 0; j < 8; ++j) {
    mu[j] = muS[(t & 7) * 8 + j];
    iv[j] = ivS[(t & 7) * 8 + j];
  }
  #pragma unroll
  for (int i = 0; i < 8; ++i) {
    const int n = ns * 256 + (t >> 3) + i * 32;
    unsigned short* p = &H[((size_t)b * N + n) * 512 + c0];
    short8 hv = *(const short8*)p;
    #pragma unroll
    for (int j = 0; j < 8; ++j) {
      const float f = fmaxf((bf2f((unsigned short)hv[j]) - mu[j]) * iv[j], 0.f);
      hv[j] = (short)f2bf(f);
    }
    *(short8*)p = hv;
  }
}

// ---------------------------------------------------------------------------
extern "C" void kernel_launch(void* const* d_in, const int* in_sizes, int n_in,
                              void* d_out, int out_size, void* d_ws, size_t ws_size,
                              hipStream_t stream)
{
  const int B = 2, D = 256, N = 4096;

  const float* x   = (const float*)d_in[0];
  const float* src = (const float*)d_in[1];
  const float* Wq  = (const float*)d_in[2];  const float* bq = (const float*)d_in[3];
  const float* Wk  = (const float*)d_in[4];  const float* bk = (const float*)d_in[5];
  const float* Wv  = (const float*)d_in[6];  const float* bv = (const float*)d_in[7];
  const float* Wm  = (const float*)d_in[8];  const float* bm = (const float*)d_in[9];
  const float* W1  = (const float*)d_in[10]; const float* b1 = (const float*)d_in[11];
  const float* W2  = (const float*)d_in[12]; const float* b2 = (const float*)d_in[13];
  float* out = (float*)d_out;

  char* ws = (char*)d_ws;
  const size_t MB = 1u << 20;
  unsigned short* xb  = (unsigned short*)(ws + 0 * MB);    // [b][n][256] bf16
  unsigned short* sb  = (unsigned short*)(ws + 4 * MB);
  unsigned short* qbf = (unsigned short*)(ws + 8 * MB);    // head-major NHC
  unsigned short* kbf = (unsigned short*)(ws + 12 * MB);
  unsigned short* vhb = (unsigned short*)(ws + 16 * MB);   // [b][h][d][n]
  unsigned short* atb = (unsigned short*)(ws + 20 * MB);   // head-major NHC
  // Opart (24..41 MB) temporally overlaps msb/hb (dead during attention)
  unsigned short* Opart = (unsigned short*)(ws + 24 * MB); // 16.78 MB bf16
  unsigned short* msb = (unsigned short*)(ws + 24 * MB);   // NHC 256 (post-combine)
  unsigned short* hb  = (unsigned short*)(ws + 28 * MB);   // [b][n][512]
  float* liPart = (float*)(ws + 41 * MB);                  // 524 KB
  unsigned short* wqkvb = (unsigned short*)(ws + 42 * MB); // [768][256]
  unsigned short* wmb = wqkvb + 768 * 256;
  unsigned short* w1b = wmb + 256 * 256;                   // [512][512]
  unsigned short* w2b = w1b + 512 * 512;                   // [256][512]
  float* biasb = (float*)(ws + 44 * MB);                   // 1792 floats
  float* Ps    = biasb + 2048;                             // 16384 floats
  float* Ps2   = Ps + 16 * 2 * 512;

  const dim3 blk(256);

  tx_all<<<dim3(N / 32, D / 32, 2 * B), blk, 0, stream>>>(x, src, xb, sb, D, N);
  wprep<<<dim3(2567), blk, 0, stream>>>(Wq, Wk, Wv, Wm, W1, W2,
                                        bq, bk, bv, bm, b1, b2,
                                        wqkvb, wmb, w1b, w2b, biasb);

  // fused q/k/v: Co=768, o<256 reads xb (q), else sb (k,v)  [BN=128, 3/CU]
  gemmT<128><<<dim3(N / 128, 12, B), blk, 0, stream>>>(
      wqkvb, biasb, xb, sb, qbf, kbf, vhb, 768, 256, 256, N, 1);

  attn_mfma<<<dim3(N / 128, 4, B * 4), blk, 0, stream>>>(
      qbf, kbf, vhb, Opart, liPart, N);
  attn_combine<<<dim3(N / 128, 4, B), blk, 0, stream>>>(Opart, liPart, atb, N);

  // message (cols head-major-permuted to match atb)  [BN=64: 512 blocks]
  gemmT<64><<<dim3(N / 64, 4, B), blk, 0, stream>>>(
      wmb, biasb + 768, atb, atb, msb, nullptr, nullptr, 256, 256, 256, N, 0);

  // h = W1 @ [x; msg]  [BN=64: 1024 blocks]
  gemmT<64><<<dim3(N / 64, 8, B), blk, 0, stream>>>(
      w1b, biasb + 1024, xb, msb, hb, nullptr, nullptr, 512, 512, 256, N, 0);

  in_stats<<<dim3(8, 16, B), blk, 0, stream>>>(hb, Ps, Ps2, N);
  in_norm<<<dim3(8, 16, B), blk, 0, stream>>>(hb, Ps, Ps2, N);

  // out = W2 @ h (fp32 CHN)  [BN=64: 512 blocks]
  gemmT<64><<<dim3(N / 64, 4, B), blk, 0, stream>>>(
      w2b, biasb + 1536, hb, hb, out, nullptr, nullptr, 256, 512, 512, N, 2);
}

// Round 11
// 205.806 us; speedup vs baseline: 1.0262x; 1.0114x over previous
//
#include <hip/hip_runtime.h>
#include <cstdint>
#include <cstddef>

// fp32 I/O. Internals: bf16 NHC activations + MFMA everywhere.
// mfma_f32_16x16x32_bf16 layouts (HW-verified m89/m120):
//   A: m=lane&15, k=quad*8+j   B: n=lane&15, k=quad*8+j
//   C/D: col(n)=lane&15, row(m)=quad*4+reg
// LDS tiles [row][64] bf16, XOR swizzle applied to the GLOBAL source chunk
// (sg = pg ^ (row&7)); involutive, frag reads conflict-free.
// Softmax: fixed-shift exp2, log2(e)/8 folded into Wq/bq. Split-K additive.
// r2 (220.2us): PV via K=32 MFMA (permlane32/16 P redistribution); li on
// MFMA pipe (ones-B-frag); attn K/V double-buffered, 1 barrier/tile.
// r7/r8 (208.9us): gemm o-tile 128->64 (occupancy win +11.3us).
// r9/r10 (208.2us): n-tile 128->64 for msg/h/W2 gemms; r10 resubmit
// confirmed r9's slow attn was a slow-clock acquire (attn back to 70.8).
// r11: in_norm pass DELETED. in_stats final stage atomicAdds per-channel
// totals (zeroed in wprep); W2 gemm normalizes its B-frags in-register
// post-LDS-read: frag holds 8 consecutive channels (k0 + (4hh+qd)*8 + j;
// source-swizzle cancels on read), apply relu(fma(x, iv, -mu*iv)) + cvtpk
// with iv/-mu*iv precomputed into 4KB LDS once per block. Staging unchanged.
// Saves one launch + 17MB of hb traffic; W2's added VALU hides under its
// latency-bound schedule (2 blocks/CU).

typedef __attribute__((ext_vector_type(8))) short short8;
typedef __attribute__((ext_vector_type(4))) float floatx4;

union U4 { unsigned int u[4]; short8 s; };

__device__ __forceinline__ unsigned short f2bf(float x) {
  union { float f; unsigned int u; } c; c.f = x;
  unsigned int r = c.u + 0x7FFFu + ((c.u >> 16) & 1u);   // RNE
  return (unsigned short)(r >> 16);
}
__device__ __forceinline__ float bf2f(unsigned short u) {
  union { unsigned int i; float f; } c; c.i = ((unsigned int)u) << 16; return c.f;
}
__device__ __forceinline__ void gload16(const void* g, void* l) {
  __builtin_amdgcn_global_load_lds(
      (const __attribute__((address_space(1))) unsigned int*)g,
      (__attribute__((address_space(3))) unsigned int*)l, 16, 0, 0);
}
// packed f32x2 -> bf16x2 (RNE), lo = s0, hi = s1
__device__ __forceinline__ unsigned int cvtpk(float lo, float hi) {
  unsigned int r;
  asm("v_cvt_pk_bf16_f32 %0, %1, %2" : "=v"(r) : "v"(lo), "v"(hi));
  return r;
}

#define LOG2E_8 0.18033688011112042f

// ---------------------------------------------------------------------------
// Transpose+convert both inputs: [b][c][n] fp32 -> [b][n][c] bf16.
// Grid (N/32, C/32, 2*B): z = which*2 + b.
// ---------------------------------------------------------------------------
__global__ __launch_bounds__(256) void tx_all(
    const float* __restrict__ x, const float* __restrict__ src,
    unsigned short* __restrict__ xb, unsigned short* __restrict__ sb,
    int C, int N)
{
  __shared__ float tile[32][33];
  const int which = blockIdx.z >> 1, b = blockIdx.z & 1;
  const float* X = which ? src : x;
  unsigned short* Y = which ? sb : xb;
  const int n0 = blockIdx.x * 32, c0 = blockIdx.y * 32;
  const int tc = threadIdx.x & 31, tr = threadIdx.x >> 5;
  #pragma unroll
  for (int i = 0; i < 4; ++i)
    tile[tr + i * 8][tc] = X[((size_t)b * C + c0 + tr + i * 8) * N + n0 + tc];
  __syncthreads();
  #pragma unroll
  for (int i = 0; i < 4; ++i)
    Y[((size_t)b * N + n0 + tr + i * 8) * C + c0 + tc] = f2bf(tile[tc][tr + i * 8]);
}

// ---------------------------------------------------------------------------
// All weight+bias converts in ONE dispatch. Grid 2568 blocks.
// wqkv rows head-major (o' = h*64+d reads o = 4*d+h); Wq/bq scaled log2e/8;
// Wm columns head-major. Last block zeroes the InstanceNorm total
// accumulators PsT/Ps2T (2x1024 floats).
// ---------------------------------------------------------------------------
__global__ __launch_bounds__(256) void wprep(
    const float* __restrict__ Wq, const float* __restrict__ Wk,
    const float* __restrict__ Wv, const float* __restrict__ Wm,
    const float* __restrict__ W1, const float* __restrict__ W2,
    const float* __restrict__ bq, const float* __restrict__ bk,
    const float* __restrict__ bv, const float* __restrict__ bm,
    const float* __restrict__ b1, const float* __restrict__ b2,
    unsigned short* __restrict__ wqkv, unsigned short* __restrict__ wm_,
    unsigned short* __restrict__ w1_, unsigned short* __restrict__ w2_,
    float* __restrict__ biasb, float* __restrict__ PsT,
    float* __restrict__ Ps2T)
{
  const int bid = blockIdx.x, t = threadIdx.x;
  if (bid < 768) {
    const int idx = bid * 256 + t;
    const int op = idx >> 8, ip = idx & 255;
    const int grp = op >> 8, oo = op & 255;
    const int o = 4 * (oo & 63) + (oo >> 6);
    const float* W = grp == 0 ? Wq : grp == 1 ? Wk : Wv;
    const float sc = grp == 0 ? LOG2E_8 : 1.f;
    wqkv[idx] = f2bf(W[(size_t)o * 256 + ip] * sc);
  } else if (bid < 1024) {
    const int idx = (bid - 768) * 256 + t;
    const int op = idx >> 8, ip = idx & 255;
    const int i2 = 4 * (ip & 63) + (ip >> 6);
    wm_[idx] = f2bf(Wm[(size_t)op * 256 + i2]);
  } else if (bid < 2048) {
    const int idx = (bid - 1024) * 256 + t;
    w1_[idx] = f2bf(W1[idx]);
  } else if (bid < 2560) {
    const int idx = (bid - 2048) * 256 + t;
    w2_[idx] = f2bf(W2[idx]);
  } else if (bid < 2567) {
    const int z = (bid - 2560) * 256 + t;
    if (z < 256)       biasb[z] = bq[4 * (z & 63) + (z >> 6)] * LOG2E_8;
    else if (z < 512)  { const int y = z - 256; biasb[z] = bk[4 * (y & 63) + (y >> 6)]; }
    else if (z < 768)  { const int y = z - 512; biasb[z] = bv[4 * (y & 63) + (y >> 6)]; }
    else if (z < 1024) biasb[z] = bm[z - 768];
    else if (z < 1536) biasb[z] = b1[z - 1024];
    else if (z < 1792) biasb[z] = b2[z - 1536];
  } else {
    #pragma unroll
    for (int k = 0; k < 4; ++k) {
      PsT[k * 256 + t] = 0.f;
      Ps2T[k * 256 + t] = 0.f;
    }
  }
}

// ---------------------------------------------------------------------------
// 64(o) x BN(n)-tile MFMA GEMM, global_load_lds staging, single-buffered.
// 4 waves as 2(o) x 2(n); wave w owns o-half (w>>1)*32, n-half (w&1)*(BN/2)
// -> 32 x BN/2, 2 x (BN/32) frags. C[b,o,n] = sum_i W[o,i]*X[b,n,i] + bias.
// Grid (N/BN, Co/64, B).
// variant 0: NHC bf16 out O0; 1: fused qkv (q->O0, k->O1, v->O2 [b][h][d][n]);
// 2: CHN fp32 out O0.
// NRM: InstanceNorm fused into the X operand — B-frags hold 8 consecutive
// channels (c = k0 + (4hh+qd)*8 + j; source-swizzle cancels on read), so
// relu((x-mu)*iv) is applied in-register post-LDS-read via
// fma(x, iv, -mu*iv) with per-channel iv/-mu*iv precomputed in LDS.
// ---------------------------------------------------------------------------
template<int BN, bool NRM>
__global__ __launch_bounds__(256) void gemmT(
    const unsigned short* __restrict__ Wb, const float* __restrict__ bias,
    const unsigned short* __restrict__ X0, const unsigned short* __restrict__ X1,
    void* __restrict__ O0, void* __restrict__ O1, void* __restrict__ O2,
    const float* __restrict__ PsT, const float* __restrict__ Ps2T,
    int Co, int Ci, int Ci0, int N, int variant)
{
  constexpr int NJ = BN / 32;        // n-frags per wave (4 or 2)
  const int n0 = blockIdx.x * BN;
  const int o0 = blockIdx.y * 64;
  const int b  = blockIdx.z;
  const int t  = threadIdx.x;
  const int w = t >> 6, lane = t & 63, qd = lane >> 4, l = lane & 15;
  const int oh = (w >> 1) * 32, nh = (w & 1) * (BN / 2);

  __shared__ unsigned short Wl[64 * 64];
  __shared__ unsigned short Xl[BN * 64];
  __shared__ float aS[NRM ? 512 : 1];   // iv[c]
  __shared__ float bS[NRM ? 512 : 1];   // -mu[c]*iv[c]

  if constexpr (NRM) {
    const float invN = 1.f / (float)N;
    for (int c = t; c < Ci; c += 256) {
      const float s  = PsT [(size_t)b * Ci + c];
      const float s2 = Ps2T[(size_t)b * Ci + c];
      const float mu = s * invN;
      const float var = fmaxf(s2 * invN - mu * mu, 0.f);
      const float iv = rsqrtf(var + 1e-5f);
      aS[c] = iv;
      bS[c] = -mu * iv;
    }
  }

  floatx4 acc[2][NJ];
  #pragma unroll
  for (int i = 0; i < 2; ++i)
    #pragma unroll
    for (int j = 0; j < NJ; ++j) acc[i][j] = (floatx4){0.f, 0.f, 0.f, 0.f};

  for (int k0 = 0; k0 < Ci; k0 += 64) {
    const unsigned short* Xs; int cb, rl;
    if (variant == 1) { Xs = (o0 < 256) ? X0 : X1; cb = k0; rl = Ci; }
    else if (k0 < Ci0) { Xs = X0; cb = k0; rl = Ci0; }
    else               { Xs = X1; cb = k0 - Ci0; rl = Ci - Ci0; }
    __syncthreads();
    #pragma unroll
    for (int i = 0; i < 2; ++i) {
      const int idx = i * 256 + t;
      const int row = idx >> 3, pg = idx & 7, sg = pg ^ (row & 7);
      gload16(&Wb[(size_t)(o0 + row) * Ci + k0 + sg * 8], &Wl[row * 64 + pg * 8]);
    }
    #pragma unroll
    for (int i = 0; i < BN / 32; ++i) {
      const int idx = i * 256 + t;
      const int row = idx >> 3, pg = idx & 7, sg = pg ^ (row & 7);
      gload16(&Xs[((size_t)b * N + n0 + row) * rl + cb + sg * 8], &Xl[row * 64 + pg * 8]);
    }
    __syncthreads();

    short8 af[2][2], bf[NJ][2];
    #pragma unroll
    for (int i = 0; i < 2; ++i) {
      const int ar = oh + 16 * i + l;
      af[i][0] = *(const short8*)&Wl[ar * 64 + ((qd ^ (ar & 7))) * 8];
      af[i][1] = *(const short8*)&Wl[ar * 64 + (((4 + qd) ^ (ar & 7))) * 8];
    }
    #pragma unroll
    for (int j = 0; j < NJ; ++j) {
      const int br = nh + 16 * j + l;
      bf[j][0] = *(const short8*)&Xl[br * 64 + ((qd ^ (br & 7))) * 8];
      bf[j][1] = *(const short8*)&Xl[br * 64 + (((4 + qd) ^ (br & 7))) * 8];
    }
    if constexpr (NRM) {
      // normalize+relu the X frags in-register; channels are consecutive.
      #pragma unroll
      for (int j = 0; j < NJ; ++j)
        #pragma unroll
        for (int hh = 0; hh < 2; ++hh) {
          const int cc = k0 + (hh * 4 + qd) * 8;
          const short8 v = bf[j][hh];
          U4 pu;
          #pragma unroll
          for (int e = 0; e < 4; ++e) {
            const float f0 = fmaxf(
                fmaf(bf2f((unsigned short)v[2 * e]), aS[cc + 2 * e], bS[cc + 2 * e]), 0.f);
            const float f1 = fmaxf(
                fmaf(bf2f((unsigned short)v[2 * e + 1]), aS[cc + 2 * e + 1], bS[cc + 2 * e + 1]), 0.f);
            pu.u[e] = cvtpk(f0, f1);
          }
          bf[j][hh] = pu.s;
        }
    }
    #pragma unroll
    for (int i = 0; i < 2; ++i)
      #pragma unroll
      for (int j = 0; j < NJ; ++j) {
        acc[i][j] = __builtin_amdgcn_mfma_f32_16x16x32_bf16(af[i][0], bf[j][0], acc[i][j], 0, 0, 0);
        acc[i][j] = __builtin_amdgcn_mfma_f32_16x16x32_bf16(af[i][1], bf[j][1], acc[i][j], 0, 0, 0);
      }
  }

  const int osec = o0 + oh;
  #pragma unroll
  for (int i = 0; i < 2; ++i) {
    const int o4 = o0 + oh + 16 * i + qd * 4;
    const float4 bi = *(const float4*)&bias[o4];
    #pragma unroll
    for (int j = 0; j < NJ; ++j) {
      const int n = n0 + nh + 16 * j + l;
      if (variant == 0) {
        unsigned short* C = (unsigned short*)O0;
        ushort4 pk;
        pk.x = f2bf(acc[i][j][0] + bi.x); pk.y = f2bf(acc[i][j][1] + bi.y);
        pk.z = f2bf(acc[i][j][2] + bi.z); pk.w = f2bf(acc[i][j][3] + bi.w);
        *(ushort4*)&C[((size_t)b * N + n) * Co + o4] = pk;
      } else if (variant == 1) {
        if (osec < 256) {
          unsigned short* C = (unsigned short*)O0;
          ushort4 pk;
          pk.x = f2bf(acc[i][j][0] + bi.x); pk.y = f2bf(acc[i][j][1] + bi.y);
          pk.z = f2bf(acc[i][j][2] + bi.z); pk.w = f2bf(acc[i][j][3] + bi.w);
          *(ushort4*)&C[((size_t)b * N + n) * 256 + o4] = pk;
        } else if (osec < 512) {
          unsigned short* C = (unsigned short*)O1;
          ushort4 pk;
          pk.x = f2bf(acc[i][j][0] + bi.x); pk.y = f2bf(acc[i][j][1] + bi.y);
          pk.z = f2bf(acc[i][j][2] + bi.z); pk.w = f2bf(acc[i][j][3] + bi.w);
          *(ushort4*)&C[((size_t)b * N + n) * 256 + (o4 - 256)] = pk;
        } else {
          unsigned short* C = (unsigned short*)O2;
          #pragma unroll
          for (int rg = 0; rg < 4; ++rg) {
            const int op = o4 - 512 + rg, h = op >> 6, d = op & 63;
            C[(((size_t)b * 4 + h) * 64 + d) * N + n] =
                f2bf(acc[i][j][rg] + ((const float*)&bi)[rg]);
          }
        }
      } else {
        float* C = (float*)O0;
        #pragma unroll
        for (int rg = 0; rg < 4; ++rg)
          C[((size_t)b * Co + o4 + rg) * N + n] = acc[i][j][rg] + ((const float*)&bi)[rg];
      }
    }
  }
}

// ---------------------------------------------------------------------------
// MFMA flash attention, split-K x4, 128 q/block (r2 version, 70-72us x16).
// QK^T operand-swapped: S^T = mfma(K, Q); lane (qd,l) holds
// S^T[key = 16js + 4qd + rg][q = 16w + l]. After exp2 + cvtpk, permlane
// 32/16 swaps redistribute to the K=32 A-frag (keys 32js2 + 8qd + j).
// PV: 16 K=32 MFMAs/tile, V read as 8 conflict-free b128/tile. li on the
// MFMA pipe (ones-B-frag). K/V double-buffered in LDS, one barrier per tile,
// prefetch in flight under compute. Writes UNNORMALIZED bf16 O partial +
// fp32 li partial. Grid (N/128, H, B*4): z = b*4 + s.
// ---------------------------------------------------------------------------
__global__ __launch_bounds__(256) void attn_mfma(
    const unsigned short* __restrict__ qb, const unsigned short* __restrict__ kb,
    const unsigned short* __restrict__ vh, unsigned short* __restrict__ Opart,
    float* __restrict__ liPart, int N)
{
  const int qt = blockIdx.x;
  const int h  = blockIdx.y;
  const int b  = blockIdx.z >> 2, s = blockIdx.z & 3;
  const int n0 = qt * 128;
  const int t  = threadIdx.x;
  const int w = t >> 6, lane = t & 63, qd = lane >> 4, l = lane & 15;

  __shared__ unsigned short Kl[2][64 * 64];  // [key][d] swizzled, double-buffered
  __shared__ unsigned short Vl[2][64 * 64];  // [d][key] swizzled, double-buffered

  // Q B-frags (n = q = l) for 2 q-sets (rows 16w+l and 64+16w+l)
  const unsigned short* qp0 = &qb[((size_t)b * N + n0 + 16 * w + l) * 256 + h * 64];
  const unsigned short* qp1 = qp0 + (size_t)64 * 256;
  short8 bQ[2][2];
  bQ[0][0] = *(const short8*)&qp0[qd * 8];
  bQ[0][1] = *(const short8*)&qp0[32 + qd * 8];
  bQ[1][0] = *(const short8*)&qp1[qd * 8];
  bQ[1][1] = *(const short8*)&qp1[32 + qd * 8];

  short8 ones;
  #pragma unroll
  for (int i = 0; i < 8; ++i) ones[i] = (short)0x3F80;   // bf16 1.0

  floatx4 accO[2][4];
  floatx4 accLi[2];
  #pragma unroll
  for (int qs = 0; qs < 2; ++qs) {
    accLi[qs] = (floatx4){0.f, 0.f, 0.f, 0.f};
    #pragma unroll
    for (int ds = 0; ds < 4; ++ds) accO[qs][ds] = (floatx4){0.f, 0.f, 0.f, 0.f};
  }

  const int j0base = s * 1024;

  auto STAGE = [&](int buf, int j0) {
    #pragma unroll
    for (int i = 0; i < 2; ++i) {
      const int idx = i * 256 + t;
      const int row = idx >> 3, pg = idx & 7, sg = pg ^ (row & 7);
      gload16(&kb[((size_t)b * N + j0 + row) * 256 + h * 64 + sg * 8],
              &Kl[buf][row * 64 + pg * 8]);
      gload16(&vh[(((size_t)b * 4 + h) * 64 + row) * N + j0 + sg * 8],
              &Vl[buf][row * 64 + pg * 8]);
    }
  };

  STAGE(0, j0base);

  #pragma unroll 2
  for (int jt = 0; jt < 16; ++jt) {
    const int cur = jt & 1;
    __syncthreads();                 // buf[cur] staged; all reads of buf[cur^1] done
    if (jt < 15) STAGE(cur ^ 1, j0base + (jt + 1) * 64);  // prefetch under compute

    // ---- QK^T, both q-sets, kf transient per js ----
    floatx4 S[2][4];
    __builtin_amdgcn_s_setprio(1);
    #pragma unroll
    for (int js = 0; js < 4; ++js) {
      const int br = 16 * js + l;
      const short8 k0 = *(const short8*)&Kl[cur][br * 64 + ((qd ^ (br & 7))) * 8];
      const short8 k1 = *(const short8*)&Kl[cur][br * 64 + (((4 + qd) ^ (br & 7))) * 8];
      floatx4 a0 = (floatx4){0.f, 0.f, 0.f, 0.f};
      floatx4 a1 = (floatx4){0.f, 0.f, 0.f, 0.f};
      a0 = __builtin_amdgcn_mfma_f32_16x16x32_bf16(k0, bQ[0][0], a0, 0, 0, 0);
      a1 = __builtin_amdgcn_mfma_f32_16x16x32_bf16(k0, bQ[1][0], a1, 0, 0, 0);
      a0 = __builtin_amdgcn_mfma_f32_16x16x32_bf16(k1, bQ[0][1], a0, 0, 0, 0);
      a1 = __builtin_amdgcn_mfma_f32_16x16x32_bf16(k1, bQ[1][1], a1, 0, 0, 0);
      S[0][js] = a0; S[1][js] = a1;
    }
    __builtin_amdgcn_s_setprio(0);

    // ---- softmax + in-register K=32 A-frag assembly ----
    unsigned int T[2][2][4];   // [qs][js2][reg]
    #pragma unroll
    for (int qs = 0; qs < 2; ++qs) {
      unsigned int U[4], W[4];
      #pragma unroll
      for (int js = 0; js < 4; ++js) {
        const float p0 = __builtin_exp2f(S[qs][js][0]);
        const float p1 = __builtin_exp2f(S[qs][js][1]);
        const float p2 = __builtin_exp2f(S[qs][js][2]);
        const float p3 = __builtin_exp2f(S[qs][js][3]);
        U[js] = cvtpk(p0, p1);
        W[js] = cvtpk(p2, p3);
      }
      #pragma unroll
      for (int js2 = 0; js2 < 2; ++js2) {
        unsigned int t0 = U[2 * js2], t2 = U[2 * js2 + 1];
        asm("v_permlane32_swap_b32 %0, %1" : "+v"(t0), "+v"(t2));
        asm("v_permlane16_swap_b32 %0, %1" : "+v"(t0), "+v"(t2));
        unsigned int t1 = W[2 * js2], t3 = W[2 * js2 + 1];
        asm("v_permlane32_swap_b32 %0, %1" : "+v"(t1), "+v"(t3));
        asm("v_permlane16_swap_b32 %0, %1" : "+v"(t1), "+v"(t3));
        T[qs][js2][0] = t0; T[qs][js2][1] = t1;
        T[qs][js2][2] = t2; T[qs][js2][3] = t3;
      }
    }

    // ---- PV + li, K=32, vv transient per js2 ----
    __builtin_amdgcn_s_setprio(1);
    #pragma unroll
    for (int js2 = 0; js2 < 2; ++js2) {
      short8 vv[4];
      #pragma unroll
      for (int ds = 0; ds < 4; ++ds) {
        const int vr = 16 * ds + l;
        vv[ds] = *(const short8*)&Vl[cur][vr * 64 + (((4 * js2 + qd) ^ (vr & 7))) * 8];
      }
      #pragma unroll
      for (int qs = 0; qs < 2; ++qs) {
        U4 pu;
        pu.u[0] = T[qs][js2][0]; pu.u[1] = T[qs][js2][1];
        pu.u[2] = T[qs][js2][2]; pu.u[3] = T[qs][js2][3];
        const short8 pa = pu.s;
        #pragma unroll
        for (int ds = 0; ds < 4; ++ds)
          accO[qs][ds] = __builtin_amdgcn_mfma_f32_16x16x32_bf16(pa, vv[ds], accO[qs][ds], 0, 0, 0);
        accLi[qs] = __builtin_amdgcn_mfma_f32_16x16x32_bf16(pa, ones, accLi[qs], 0, 0, 0);
      }
    }
    __builtin_amdgcn_s_setprio(0);
  }

  // epilogue: unnormalized partials. accO row = q = qs*64 + 16w + 4qd + rg.
  const size_t obase = ((((size_t)b * 4 + h) * 4 + s) * 32 + qt) * 128;
  #pragma unroll
  for (int qs = 0; qs < 2; ++qs)
    #pragma unroll
    for (int rg = 0; rg < 4; ++rg) {
      const int q = qs * 64 + 16 * w + qd * 4 + rg;
      #pragma unroll
      for (int ds = 0; ds < 4; ++ds)
        Opart[(obase + q) * 64 + 16 * ds + l] = f2bf(accO[qs][ds][rg]);
      if (l == 0) liPart[obase + q] = accLi[qs][rg];
    }
}

// ---------------------------------------------------------------------------
// Combine 4 split-K partials -> atb NHC head-major bf16. Grid (N/128, H, B).
// ---------------------------------------------------------------------------
__global__ __launch_bounds__(256) void attn_combine(
    const unsigned short* __restrict__ Opart, const float* __restrict__ liPart,
    unsigned short* __restrict__ atb, int N)
{
  const int qt = blockIdx.x, h = blockIdx.y, b = blockIdx.z;
  const int t = threadIdx.x;
  const int q = t >> 1, d0 = (t & 1) * 32;

  float li = 0.f;
  size_t idx[4];
  #pragma unroll
  for (int s = 0; s < 4; ++s) {
    idx[s] = ((((size_t)b * 4 + h) * 4 + s) * 32 + qt) * 128 + q;
    li += liPart[idx[s]];
  }
  const float inv = 1.f / li;

  float o[32];
  #pragma unroll
  for (int c = 0; c < 32; ++c) o[c] = 0.f;
  #pragma unroll
  for (int s = 0; s < 4; ++s) {
    #pragma unroll
    for (int c4 = 0; c4 < 4; ++c4) {
      const short8 v = *(const short8*)&Opart[idx[s] * 64 + d0 + c4 * 8];
      #pragma unroll
      for (int j = 0; j < 8; ++j) o[c4 * 8 + j] += bf2f((unsigned short)v[j]);
    }
  }
  unsigned short* dst = &atb[((size_t)b * N + qt * 128 + q) * 256 + h * 64 + d0];
  #pragma unroll
  for (int c4 = 0; c4 < 4; ++c4) {
    ushort4 pk;
    pk.x = f2bf(o[c4 * 8 + 0] * inv); pk.y = f2bf(o[c4 * 8 + 1] * inv);
    pk.z = f2bf(o[c4 * 8 + 2] * inv); pk.w = f2bf(o[c4 * 8 + 3] * inv);
    *(ushort4*)&dst[c4 * 8] = pk;
    pk.x = f2bf(o[c4 * 8 + 4] * inv); pk.y = f2bf(o[c4 * 8 + 5] * inv);
    pk.z = f2bf(o[c4 * 8 + 6] * inv); pk.w = f2bf(o[c4 * 8 + 7] * inv);
    *(ushort4*)&dst[c4 * 8 + 4] = pk;
  }
}

// ---------------------------------------------------------------------------
// InstanceNorm stats on NHC h [b][n][512]: per-slice partial sums reduced in
// LDS, then atomicAdd into per-channel totals PsT/Ps2T (zeroed by wprep).
// ---------------------------------------------------------------------------
__global__ __launch_bounds__(256) void in_stats(
    const unsigned short* __restrict__ H, float* __restrict__ PsT,
    float* __restrict__ Ps2T, int N)
{
  const int cg = blockIdx.x, ns = blockIdx.y, b = blockIdx.z, t = threadIdx.x;
  const int c0 = cg * 64 + (t & 7) * 8;
  float s[8] = {}, s2[8] = {};
  #pragma unroll
  for (int i = 0; i < 8; ++i) {
    const int n = ns * 256 + (t >> 3) + i * 32;
    const short8 hv = *(const short8*)&H[((size_t)b * N + n) * 512 + c0];
    #pragma unroll
    for (int j = 0; j < 8; ++j) {
      const float f = bf2f((unsigned short)hv[j]);
      s[j] += f; s2[j] += f * f;
    }
  }
  __shared__ float rs[32][64], rs2[32][64];
  #pragma unroll
  for (int j = 0; j < 8; ++j) {
    rs[t >> 3][(t & 7) * 8 + j] = s[j];
    rs2[t >> 3][(t & 7) * 8 + j] = s2[j];
  }
  __syncthreads();
  if (t < 64) {
    float a = 0.f, a2 = 0.f;
    #pragma unroll
    for (int r = 0; r < 32; ++r) { a += rs[r][t]; a2 += rs2[r][t]; }
    const int c = cg * 64 + t;
    atomicAdd(&PsT [(size_t)b * 512 + c], a);
    atomicAdd(&Ps2T[(size_t)b * 512 + c], a2);
  }
}

// ---------------------------------------------------------------------------
extern "C" void kernel_launch(void* const* d_in, const int* in_sizes, int n_in,
                              void* d_out, int out_size, void* d_ws, size_t ws_size,
                              hipStream_t stream)
{
  const int B = 2, D = 256, N = 4096;

  const float* x   = (const float*)d_in[0];
  const float* src = (const float*)d_in[1];
  const float* Wq  = (const float*)d_in[2];  const float* bq = (const float*)d_in[3];
  const float* Wk  = (const float*)d_in[4];  const float* bk = (const float*)d_in[5];
  const float* Wv  = (const float*)d_in[6];  const float* bv = (const float*)d_in[7];
  const float* Wm  = (const float*)d_in[8];  const float* bm = (const float*)d_in[9];
  const float* W1  = (const float*)d_in[10]; const float* b1 = (const float*)d_in[11];
  const float* W2  = (const float*)d_in[12]; const float* b2 = (const float*)d_in[13];
  float* out = (float*)d_out;

  char* ws = (char*)d_ws;
  const size_t MB = 1u << 20;
  unsigned short* xb  = (unsigned short*)(ws + 0 * MB);    // [b][n][256] bf16
  unsigned short* sb  = (unsigned short*)(ws + 4 * MB);
  unsigned short* qbf = (unsigned short*)(ws + 8 * MB);    // head-major NHC
  unsigned short* kbf = (unsigned short*)(ws + 12 * MB);
  unsigned short* vhb = (unsigned short*)(ws + 16 * MB);   // [b][h][d][n]
  unsigned short* atb = (unsigned short*)(ws + 20 * MB);   // head-major NHC
  // Opart (24..41 MB) temporally overlaps msb/hb (dead during attention)
  unsigned short* Opart = (unsigned short*)(ws + 24 * MB); // 16.78 MB bf16
  unsigned short* msb = (unsigned short*)(ws + 24 * MB);   // NHC 256 (post-combine)
  unsigned short* hb  = (unsigned short*)(ws + 28 * MB);   // [b][n][512] RAW h
  float* liPart = (float*)(ws + 41 * MB);                  // 524 KB
  unsigned short* wqkvb = (unsigned short*)(ws + 42 * MB); // [768][256]
  unsigned short* wmb = wqkvb + 768 * 256;
  unsigned short* w1b = wmb + 256 * 256;                   // [512][512]
  unsigned short* w2b = w1b + 512 * 512;                   // [256][512]
  float* biasb = (float*)(ws + 44 * MB);                   // 1792 floats
  float* PsT   = biasb + 2048;                             // [B][512] totals
  float* Ps2T  = PsT + 1024;                               // [B][512] totals

  const dim3 blk(256);

  tx_all<<<dim3(N / 32, D / 32, 2 * B), blk, 0, stream>>>(x, src, xb, sb, D, N);
  wprep<<<dim3(2568), blk, 0, stream>>>(Wq, Wk, Wv, Wm, W1, W2,
                                        bq, bk, bv, bm, b1, b2,
                                        wqkvb, wmb, w1b, w2b, biasb, PsT, Ps2T);

  // fused q/k/v: Co=768, o<256 reads xb (q), else sb (k,v)  [BN=128, 3/CU]
  gemmT<128, false><<<dim3(N / 128, 12, B), blk, 0, stream>>>(
      wqkvb, biasb, xb, sb, qbf, kbf, vhb, nullptr, nullptr, 768, 256, 256, N, 1);

  attn_mfma<<<dim3(N / 128, 4, B * 4), blk, 0, stream>>>(
      qbf, kbf, vhb, Opart, liPart, N);
  attn_combine<<<dim3(N / 128, 4, B), blk, 0, stream>>>(Opart, liPart, atb, N);

  // message (cols head-major-permuted to match atb)  [BN=64: 512 blocks]
  gemmT<64, false><<<dim3(N / 64, 4, B), blk, 0, stream>>>(
      wmb, biasb + 768, atb, atb, msb, nullptr, nullptr, nullptr, nullptr,
      256, 256, 256, N, 0);

  // h = W1 @ [x; msg]  [BN=64: 1024 blocks] — writes RAW h
  gemmT<64, false><<<dim3(N / 64, 8, B), blk, 0, stream>>>(
      w1b, biasb + 1024, xb, msb, hb, nullptr, nullptr, nullptr, nullptr,
      512, 512, 256, N, 0);

  in_stats<<<dim3(8, 16, B), blk, 0, stream>>>(hb, PsT, Ps2T, N);

  // out = W2 @ relu(norm(h)) — norm fused into X frags  [BN=64: 512 blocks]
  gemmT<64, true><<<dim3(N / 64, 4, B), blk, 0, stream>>>(
      w2b, biasb + 1536, hb, hb, out, nullptr, nullptr, PsT, Ps2T,
      256, 512, 512, N, 2);
}

// Round 12
// 203.271 us; speedup vs baseline: 1.0390x; 1.0125x over previous
//
#include <hip/hip_runtime.h>
#include <cstdint>
#include <cstddef>

// fp32 I/O. Internals: bf16 NHC activations + MFMA everywhere.
// mfma_f32_16x16x32_bf16 layouts (HW-verified m89/m120):
//   A: m=lane&15, k=quad*8+j   B: n=lane&15, k=quad*8+j
//   C/D: col(n)=lane&15, row(m)=quad*4+reg
// LDS tiles [row][64] bf16, XOR swizzle applied to the GLOBAL source chunk
// (sg = pg ^ (row&7)); involutive, frag reads conflict-free.
// Softmax: fixed-shift exp2, log2(e)/8 folded into Wq/bq. Split-K additive.
// r2 (220.2us): PV via K=32 MFMA (permlane32/16 P redistribution); li on
// MFMA pipe (ones-B-frag); attn K/V double-buffered, 1 barrier/tile.
// r7/r8 (208.9us): gemm o-tile 128->64 (occupancy win +11.3us).
// r9/r10 (208.2us): n-tile 128->64 for msg/h/W2 gemms (neutral-to-+).
// r11 (205.8us): in_norm pass deleted; stats via atomicAdd totals; norm
// fused into W2's X-frags (relu(fma(x,iv,-mu*iv)) post-LDS-read).
// r12 (last occupancy notch): qkv gemm BN 128->64 — the only gemm still at
// 3 blocks/CU -> 1536 blocks, 6/CU, LDS 16KB. W traffic doubles but wqkvb
// (0.4MB unique) is L2-served. attn VALU-bound at 83% combined pipes;
// pre-committed: if this is neutral, the tile-occupancy lever is exhausted.

typedef __attribute__((ext_vector_type(8))) short short8;
typedef __attribute__((ext_vector_type(4))) float floatx4;

union U4 { unsigned int u[4]; short8 s; };

__device__ __forceinline__ unsigned short f2bf(float x) {
  union { float f; unsigned int u; } c; c.f = x;
  unsigned int r = c.u + 0x7FFFu + ((c.u >> 16) & 1u);   // RNE
  return (unsigned short)(r >> 16);
}
__device__ __forceinline__ float bf2f(unsigned short u) {
  union { unsigned int i; float f; } c; c.i = ((unsigned int)u) << 16; return c.f;
}
__device__ __forceinline__ void gload16(const void* g, void* l) {
  __builtin_amdgcn_global_load_lds(
      (const __attribute__((address_space(1))) unsigned int*)g,
      (__attribute__((address_space(3))) unsigned int*)l, 16, 0, 0);
}
// packed f32x2 -> bf16x2 (RNE), lo = s0, hi = s1
__device__ __forceinline__ unsigned int cvtpk(float lo, float hi) {
  unsigned int r;
  asm("v_cvt_pk_bf16_f32 %0, %1, %2" : "=v"(r) : "v"(lo), "v"(hi));
  return r;
}

#define LOG2E_8 0.18033688011112042f

// ---------------------------------------------------------------------------
// Transpose+convert both inputs: [b][c][n] fp32 -> [b][n][c] bf16.
// Grid (N/32, C/32, 2*B): z = which*2 + b.
// ---------------------------------------------------------------------------
__global__ __launch_bounds__(256) void tx_all(
    const float* __restrict__ x, const float* __restrict__ src,
    unsigned short* __restrict__ xb, unsigned short* __restrict__ sb,
    int C, int N)
{
  __shared__ float tile[32][33];
  const int which = blockIdx.z >> 1, b = blockIdx.z & 1;
  const float* X = which ? src : x;
  unsigned short* Y = which ? sb : xb;
  const int n0 = blockIdx.x * 32, c0 = blockIdx.y * 32;
  const int tc = threadIdx.x & 31, tr = threadIdx.x >> 5;
  #pragma unroll
  for (int i = 0; i < 4; ++i)
    tile[tr + i * 8][tc] = X[((size_t)b * C + c0 + tr + i * 8) * N + n0 + tc];
  __syncthreads();
  #pragma unroll
  for (int i = 0; i < 4; ++i)
    Y[((size_t)b * N + n0 + tr + i * 8) * C + c0 + tc] = f2bf(tile[tc][tr + i * 8]);
}

// ---------------------------------------------------------------------------
// All weight+bias converts in ONE dispatch. Grid 2568 blocks.
// wqkv rows head-major (o' = h*64+d reads o = 4*d+h); Wq/bq scaled log2e/8;
// Wm columns head-major. Last block zeroes the InstanceNorm total
// accumulators PsT/Ps2T (2x1024 floats).
// ---------------------------------------------------------------------------
__global__ __launch_bounds__(256) void wprep(
    const float* __restrict__ Wq, const float* __restrict__ Wk,
    const float* __restrict__ Wv, const float* __restrict__ Wm,
    const float* __restrict__ W1, const float* __restrict__ W2,
    const float* __restrict__ bq, const float* __restrict__ bk,
    const float* __restrict__ bv, const float* __restrict__ bm,
    const float* __restrict__ b1, const float* __restrict__ b2,
    unsigned short* __restrict__ wqkv, unsigned short* __restrict__ wm_,
    unsigned short* __restrict__ w1_, unsigned short* __restrict__ w2_,
    float* __restrict__ biasb, float* __restrict__ PsT,
    float* __restrict__ Ps2T)
{
  const int bid = blockIdx.x, t = threadIdx.x;
  if (bid < 768) {
    const int idx = bid * 256 + t;
    const int op = idx >> 8, ip = idx & 255;
    const int grp = op >> 8, oo = op & 255;
    const int o = 4 * (oo & 63) + (oo >> 6);
    const float* W = grp == 0 ? Wq : grp == 1 ? Wk : Wv;
    const float sc = grp == 0 ? LOG2E_8 : 1.f;
    wqkv[idx] = f2bf(W[(size_t)o * 256 + ip] * sc);
  } else if (bid < 1024) {
    const int idx = (bid - 768) * 256 + t;
    const int op = idx >> 8, ip = idx & 255;
    const int i2 = 4 * (ip & 63) + (ip >> 6);
    wm_[idx] = f2bf(Wm[(size_t)op * 256 + i2]);
  } else if (bid < 2048) {
    const int idx = (bid - 1024) * 256 + t;
    w1_[idx] = f2bf(W1[idx]);
  } else if (bid < 2560) {
    const int idx = (bid - 2048) * 256 + t;
    w2_[idx] = f2bf(W2[idx]);
  } else if (bid < 2567) {
    const int z = (bid - 2560) * 256 + t;
    if (z < 256)       biasb[z] = bq[4 * (z & 63) + (z >> 6)] * LOG2E_8;
    else if (z < 512)  { const int y = z - 256; biasb[z] = bk[4 * (y & 63) + (y >> 6)]; }
    else if (z < 768)  { const int y = z - 512; biasb[z] = bv[4 * (y & 63) + (y >> 6)]; }
    else if (z < 1024) biasb[z] = bm[z - 768];
    else if (z < 1536) biasb[z] = b1[z - 1024];
    else if (z < 1792) biasb[z] = b2[z - 1536];
  } else {
    #pragma unroll
    for (int k = 0; k < 4; ++k) {
      PsT[k * 256 + t] = 0.f;
      Ps2T[k * 256 + t] = 0.f;
    }
  }
}

// ---------------------------------------------------------------------------
// 64(o) x BN(n)-tile MFMA GEMM, global_load_lds staging, single-buffered.
// 4 waves as 2(o) x 2(n); wave w owns o-half (w>>1)*32, n-half (w&1)*(BN/2)
// -> 32 x BN/2, 2 x (BN/32) frags. C[b,o,n] = sum_i W[o,i]*X[b,n,i] + bias.
// Grid (N/BN, Co/64, B).
// variant 0: NHC bf16 out O0; 1: fused qkv (q->O0, k->O1, v->O2 [b][h][d][n]);
// 2: CHN fp32 out O0.
// NRM: InstanceNorm fused into the X operand — B-frags hold 8 consecutive
// channels (c = k0 + (4hh+qd)*8 + j; source-swizzle cancels on read), so
// relu((x-mu)*iv) is applied in-register post-LDS-read via
// fma(x, iv, -mu*iv) with per-channel iv/-mu*iv precomputed in LDS.
// ---------------------------------------------------------------------------
template<int BN, bool NRM>
__global__ __launch_bounds__(256) void gemmT(
    const unsigned short* __restrict__ Wb, const float* __restrict__ bias,
    const unsigned short* __restrict__ X0, const unsigned short* __restrict__ X1,
    void* __restrict__ O0, void* __restrict__ O1, void* __restrict__ O2,
    const float* __restrict__ PsT, const float* __restrict__ Ps2T,
    int Co, int Ci, int Ci0, int N, int variant)
{
  constexpr int NJ = BN / 32;        // n-frags per wave (4 or 2)
  const int n0 = blockIdx.x * BN;
  const int o0 = blockIdx.y * 64;
  const int b  = blockIdx.z;
  const int t  = threadIdx.x;
  const int w = t >> 6, lane = t & 63, qd = lane >> 4, l = lane & 15;
  const int oh = (w >> 1) * 32, nh = (w & 1) * (BN / 2);

  __shared__ unsigned short Wl[64 * 64];
  __shared__ unsigned short Xl[BN * 64];
  __shared__ float aS[NRM ? 512 : 1];   // iv[c]
  __shared__ float bS[NRM ? 512 : 1];   // -mu[c]*iv[c]

  if constexpr (NRM) {
    const float invN = 1.f / (float)N;
    for (int c = t; c < Ci; c += 256) {
      const float s  = PsT [(size_t)b * Ci + c];
      const float s2 = Ps2T[(size_t)b * Ci + c];
      const float mu = s * invN;
      const float var = fmaxf(s2 * invN - mu * mu, 0.f);
      const float iv = rsqrtf(var + 1e-5f);
      aS[c] = iv;
      bS[c] = -mu * iv;
    }
  }

  floatx4 acc[2][NJ];
  #pragma unroll
  for (int i = 0; i < 2; ++i)
    #pragma unroll
    for (int j = 0; j < NJ; ++j) acc[i][j] = (floatx4){0.f, 0.f, 0.f, 0.f};

  for (int k0 = 0; k0 < Ci; k0 += 64) {
    const unsigned short* Xs; int cb, rl;
    if (variant == 1) { Xs = (o0 < 256) ? X0 : X1; cb = k0; rl = Ci; }
    else if (k0 < Ci0) { Xs = X0; cb = k0; rl = Ci0; }
    else               { Xs = X1; cb = k0 - Ci0; rl = Ci - Ci0; }
    __syncthreads();
    #pragma unroll
    for (int i = 0; i < 2; ++i) {
      const int idx = i * 256 + t;
      const int row = idx >> 3, pg = idx & 7, sg = pg ^ (row & 7);
      gload16(&Wb[(size_t)(o0 + row) * Ci + k0 + sg * 8], &Wl[row * 64 + pg * 8]);
    }
    #pragma unroll
    for (int i = 0; i < BN / 32; ++i) {
      const int idx = i * 256 + t;
      const int row = idx >> 3, pg = idx & 7, sg = pg ^ (row & 7);
      gload16(&Xs[((size_t)b * N + n0 + row) * rl + cb + sg * 8], &Xl[row * 64 + pg * 8]);
    }
    __syncthreads();

    short8 af[2][2], bf[NJ][2];
    #pragma unroll
    for (int i = 0; i < 2; ++i) {
      const int ar = oh + 16 * i + l;
      af[i][0] = *(const short8*)&Wl[ar * 64 + ((qd ^ (ar & 7))) * 8];
      af[i][1] = *(const short8*)&Wl[ar * 64 + (((4 + qd) ^ (ar & 7))) * 8];
    }
    #pragma unroll
    for (int j = 0; j < NJ; ++j) {
      const int br = nh + 16 * j + l;
      bf[j][0] = *(const short8*)&Xl[br * 64 + ((qd ^ (br & 7))) * 8];
      bf[j][1] = *(const short8*)&Xl[br * 64 + (((4 + qd) ^ (br & 7))) * 8];
    }
    if constexpr (NRM) {
      // normalize+relu the X frags in-register; channels are consecutive.
      #pragma unroll
      for (int j = 0; j < NJ; ++j)
        #pragma unroll
        for (int hh = 0; hh < 2; ++hh) {
          const int cc = k0 + (hh * 4 + qd) * 8;
          const short8 v = bf[j][hh];
          U4 pu;
          #pragma unroll
          for (int e = 0; e < 4; ++e) {
            const float f0 = fmaxf(
                fmaf(bf2f((unsigned short)v[2 * e]), aS[cc + 2 * e], bS[cc + 2 * e]), 0.f);
            const float f1 = fmaxf(
                fmaf(bf2f((unsigned short)v[2 * e + 1]), aS[cc + 2 * e + 1], bS[cc + 2 * e + 1]), 0.f);
            pu.u[e] = cvtpk(f0, f1);
          }
          bf[j][hh] = pu.s;
        }
    }
    #pragma unroll
    for (int i = 0; i < 2; ++i)
      #pragma unroll
      for (int j = 0; j < NJ; ++j) {
        acc[i][j] = __builtin_amdgcn_mfma_f32_16x16x32_bf16(af[i][0], bf[j][0], acc[i][j], 0, 0, 0);
        acc[i][j] = __builtin_amdgcn_mfma_f32_16x16x32_bf16(af[i][1], bf[j][1], acc[i][j], 0, 0, 0);
      }
  }

  const int osec = o0 + oh;
  #pragma unroll
  for (int i = 0; i < 2; ++i) {
    const int o4 = o0 + oh + 16 * i + qd * 4;
    const float4 bi = *(const float4*)&bias[o4];
    #pragma unroll
    for (int j = 0; j < NJ; ++j) {
      const int n = n0 + nh + 16 * j + l;
      if (variant == 0) {
        unsigned short* C = (unsigned short*)O0;
        ushort4 pk;
        pk.x = f2bf(acc[i][j][0] + bi.x); pk.y = f2bf(acc[i][j][1] + bi.y);
        pk.z = f2bf(acc[i][j][2] + bi.z); pk.w = f2bf(acc[i][j][3] + bi.w);
        *(ushort4*)&C[((size_t)b * N + n) * Co + o4] = pk;
      } else if (variant == 1) {
        if (osec < 256) {
          unsigned short* C = (unsigned short*)O0;
          ushort4 pk;
          pk.x = f2bf(acc[i][j][0] + bi.x); pk.y = f2bf(acc[i][j][1] + bi.y);
          pk.z = f2bf(acc[i][j][2] + bi.z); pk.w = f2bf(acc[i][j][3] + bi.w);
          *(ushort4*)&C[((size_t)b * N + n) * 256 + o4] = pk;
        } else if (osec < 512) {
          unsigned short* C = (unsigned short*)O1;
          ushort4 pk;
          pk.x = f2bf(acc[i][j][0] + bi.x); pk.y = f2bf(acc[i][j][1] + bi.y);
          pk.z = f2bf(acc[i][j][2] + bi.z); pk.w = f2bf(acc[i][j][3] + bi.w);
          *(ushort4*)&C[((size_t)b * N + n) * 256 + (o4 - 256)] = pk;
        } else {
          unsigned short* C = (unsigned short*)O2;
          #pragma unroll
          for (int rg = 0; rg < 4; ++rg) {
            const int op = o4 - 512 + rg, h = op >> 6, d = op & 63;
            C[(((size_t)b * 4 + h) * 64 + d) * N + n] =
                f2bf(acc[i][j][rg] + ((const float*)&bi)[rg]);
          }
        }
      } else {
        float* C = (float*)O0;
        #pragma unroll
        for (int rg = 0; rg < 4; ++rg)
          C[((size_t)b * Co + o4 + rg) * N + n] = acc[i][j][rg] + ((const float*)&bi)[rg];
      }
    }
  }
}

// ---------------------------------------------------------------------------
// MFMA flash attention, split-K x4, 128 q/block (r2 version, 70-72us x17).
// QK^T operand-swapped: S^T = mfma(K, Q); lane (qd,l) holds
// S^T[key = 16js + 4qd + rg][q = 16w + l]. After exp2 + cvtpk, permlane
// 32/16 swaps redistribute to the K=32 A-frag (keys 32js2 + 8qd + j).
// PV: 16 K=32 MFMAs/tile, V read as 8 conflict-free b128/tile. li on the
// MFMA pipe (ones-B-frag). K/V double-buffered in LDS, one barrier per tile,
// prefetch in flight under compute. Writes UNNORMALIZED bf16 O partial +
// fp32 li partial. Grid (N/128, H, B*4): z = b*4 + s.
// ---------------------------------------------------------------------------
__global__ __launch_bounds__(256) void attn_mfma(
    const unsigned short* __restrict__ qb, const unsigned short* __restrict__ kb,
    const unsigned short* __restrict__ vh, unsigned short* __restrict__ Opart,
    float* __restrict__ liPart, int N)
{
  const int qt = blockIdx.x;
  const int h  = blockIdx.y;
  const int b  = blockIdx.z >> 2, s = blockIdx.z & 3;
  const int n0 = qt * 128;
  const int t  = threadIdx.x;
  const int w = t >> 6, lane = t & 63, qd = lane >> 4, l = lane & 15;

  __shared__ unsigned short Kl[2][64 * 64];  // [key][d] swizzled, double-buffered
  __shared__ unsigned short Vl[2][64 * 64];  // [d][key] swizzled, double-buffered

  // Q B-frags (n = q = l) for 2 q-sets (rows 16w+l and 64+16w+l)
  const unsigned short* qp0 = &qb[((size_t)b * N + n0 + 16 * w + l) * 256 + h * 64];
  const unsigned short* qp1 = qp0 + (size_t)64 * 256;
  short8 bQ[2][2];
  bQ[0][0] = *(const short8*)&qp0[qd * 8];
  bQ[0][1] = *(const short8*)&qp0[32 + qd * 8];
  bQ[1][0] = *(const short8*)&qp1[qd * 8];
  bQ[1][1] = *(const short8*)&qp1[32 + qd * 8];

  short8 ones;
  #pragma unroll
  for (int i = 0; i < 8; ++i) ones[i] = (short)0x3F80;   // bf16 1.0

  floatx4 accO[2][4];
  floatx4 accLi[2];
  #pragma unroll
  for (int qs = 0; qs < 2; ++qs) {
    accLi[qs] = (floatx4){0.f, 0.f, 0.f, 0.f};
    #pragma unroll
    for (int ds = 0; ds < 4; ++ds) accO[qs][ds] = (floatx4){0.f, 0.f, 0.f, 0.f};
  }

  const int j0base = s * 1024;

  auto STAGE = [&](int buf, int j0) {
    #pragma unroll
    for (int i = 0; i < 2; ++i) {
      const int idx = i * 256 + t;
      const int row = idx >> 3, pg = idx & 7, sg = pg ^ (row & 7);
      gload16(&kb[((size_t)b * N + j0 + row) * 256 + h * 64 + sg * 8],
              &Kl[buf][row * 64 + pg * 8]);
      gload16(&vh[(((size_t)b * 4 + h) * 64 + row) * N + j0 + sg * 8],
              &Vl[buf][row * 64 + pg * 8]);
    }
  };

  STAGE(0, j0base);

  #pragma unroll 2
  for (int jt = 0; jt < 16; ++jt) {
    const int cur = jt & 1;
    __syncthreads();                 // buf[cur] staged; all reads of buf[cur^1] done
    if (jt < 15) STAGE(cur ^ 1, j0base + (jt + 1) * 64);  // prefetch under compute

    // ---- QK^T, both q-sets, kf transient per js ----
    floatx4 S[2][4];
    __builtin_amdgcn_s_setprio(1);
    #pragma unroll
    for (int js = 0; js < 4; ++js) {
      const int br = 16 * js + l;
      const short8 k0 = *(const short8*)&Kl[cur][br * 64 + ((qd ^ (br & 7))) * 8];
      const short8 k1 = *(const short8*)&Kl[cur][br * 64 + (((4 + qd) ^ (br & 7))) * 8];
      floatx4 a0 = (floatx4){0.f, 0.f, 0.f, 0.f};
      floatx4 a1 = (floatx4){0.f, 0.f, 0.f, 0.f};
      a0 = __builtin_amdgcn_mfma_f32_16x16x32_bf16(k0, bQ[0][0], a0, 0, 0, 0);
      a1 = __builtin_amdgcn_mfma_f32_16x16x32_bf16(k0, bQ[1][0], a1, 0, 0, 0);
      a0 = __builtin_amdgcn_mfma_f32_16x16x32_bf16(k1, bQ[0][1], a0, 0, 0, 0);
      a1 = __builtin_amdgcn_mfma_f32_16x16x32_bf16(k1, bQ[1][1], a1, 0, 0, 0);
      S[0][js] = a0; S[1][js] = a1;
    }
    __builtin_amdgcn_s_setprio(0);

    // ---- softmax + in-register K=32 A-frag assembly ----
    unsigned int T[2][2][4];   // [qs][js2][reg]
    #pragma unroll
    for (int qs = 0; qs < 2; ++qs) {
      unsigned int U[4], W[4];
      #pragma unroll
      for (int js = 0; js < 4; ++js) {
        const float p0 = __builtin_exp2f(S[qs][js][0]);
        const float p1 = __builtin_exp2f(S[qs][js][1]);
        const float p2 = __builtin_exp2f(S[qs][js][2]);
        const float p3 = __builtin_exp2f(S[qs][js][3]);
        U[js] = cvtpk(p0, p1);
        W[js] = cvtpk(p2, p3);
      }
      #pragma unroll
      for (int js2 = 0; js2 < 2; ++js2) {
        unsigned int t0 = U[2 * js2], t2 = U[2 * js2 + 1];
        asm("v_permlane32_swap_b32 %0, %1" : "+v"(t0), "+v"(t2));
        asm("v_permlane16_swap_b32 %0, %1" : "+v"(t0), "+v"(t2));
        unsigned int t1 = W[2 * js2], t3 = W[2 * js2 + 1];
        asm("v_permlane32_swap_b32 %0, %1" : "+v"(t1), "+v"(t3));
        asm("v_permlane16_swap_b32 %0, %1" : "+v"(t1), "+v"(t3));
        T[qs][js2][0] = t0; T[qs][js2][1] = t1;
        T[qs][js2][2] = t2; T[qs][js2][3] = t3;
      }
    }

    // ---- PV + li, K=32, vv transient per js2 ----
    __builtin_amdgcn_s_setprio(1);
    #pragma unroll
    for (int js2 = 0; js2 < 2; ++js2) {
      short8 vv[4];
      #pragma unroll
      for (int ds = 0; ds < 4; ++ds) {
        const int vr = 16 * ds + l;
        vv[ds] = *(const short8*)&Vl[cur][vr * 64 + (((4 * js2 + qd) ^ (vr & 7))) * 8];
      }
      #pragma unroll
      for (int qs = 0; qs < 2; ++qs) {
        U4 pu;
        pu.u[0] = T[qs][js2][0]; pu.u[1] = T[qs][js2][1];
        pu.u[2] = T[qs][js2][2]; pu.u[3] = T[qs][js2][3];
        const short8 pa = pu.s;
        #pragma unroll
        for (int ds = 0; ds < 4; ++ds)
          accO[qs][ds] = __builtin_amdgcn_mfma_f32_16x16x32_bf16(pa, vv[ds], accO[qs][ds], 0, 0, 0);
        accLi[qs] = __builtin_amdgcn_mfma_f32_16x16x32_bf16(pa, ones, accLi[qs], 0, 0, 0);
      }
    }
    __builtin_amdgcn_s_setprio(0);
  }

  // epilogue: unnormalized partials. accO row = q = qs*64 + 16w + 4qd + rg.
  const size_t obase = ((((size_t)b * 4 + h) * 4 + s) * 32 + qt) * 128;
  #pragma unroll
  for (int qs = 0; qs < 2; ++qs)
    #pragma unroll
    for (int rg = 0; rg < 4; ++rg) {
      const int q = qs * 64 + 16 * w + qd * 4 + rg;
      #pragma unroll
      for (int ds = 0; ds < 4; ++ds)
        Opart[(obase + q) * 64 + 16 * ds + l] = f2bf(accO[qs][ds][rg]);
      if (l == 0) liPart[obase + q] = accLi[qs][rg];
    }
}

// ---------------------------------------------------------------------------
// Combine 4 split-K partials -> atb NHC head-major bf16. Grid (N/128, H, B).
// ---------------------------------------------------------------------------
__global__ __launch_bounds__(256) void attn_combine(
    const unsigned short* __restrict__ Opart, const float* __restrict__ liPart,
    unsigned short* __restrict__ atb, int N)
{
  const int qt = blockIdx.x, h = blockIdx.y, b = blockIdx.z;
  const int t = threadIdx.x;
  const int q = t >> 1, d0 = (t & 1) * 32;

  float li = 0.f;
  size_t idx[4];
  #pragma unroll
  for (int s = 0; s < 4; ++s) {
    idx[s] = ((((size_t)b * 4 + h) * 4 + s) * 32 + qt) * 128 + q;
    li += liPart[idx[s]];
  }
  const float inv = 1.f / li;

  float o[32];
  #pragma unroll
  for (int c = 0; c < 32; ++c) o[c] = 0.f;
  #pragma unroll
  for (int s = 0; s < 4; ++s) {
    #pragma unroll
    for (int c4 = 0; c4 < 4; ++c4) {
      const short8 v = *(const short8*)&Opart[idx[s] * 64 + d0 + c4 * 8];
      #pragma unroll
      for (int j = 0; j < 8; ++j) o[c4 * 8 + j] += bf2f((unsigned short)v[j]);
    }
  }
  unsigned short* dst = &atb[((size_t)b * N + qt * 128 + q) * 256 + h * 64 + d0];
  #pragma unroll
  for (int c4 = 0; c4 < 4; ++c4) {
    ushort4 pk;
    pk.x = f2bf(o[c4 * 8 + 0] * inv); pk.y = f2bf(o[c4 * 8 + 1] * inv);
    pk.z = f2bf(o[c4 * 8 + 2] * inv); pk.w = f2bf(o[c4 * 8 + 3] * inv);
    *(ushort4*)&dst[c4 * 8] = pk;
    pk.x = f2bf(o[c4 * 8 + 4] * inv); pk.y = f2bf(o[c4 * 8 + 5] * inv);
    pk.z = f2bf(o[c4 * 8 + 6] * inv); pk.w = f2bf(o[c4 * 8 + 7] * inv);
    *(ushort4*)&dst[c4 * 8 + 4] = pk;
  }
}

// ---------------------------------------------------------------------------
// InstanceNorm stats on NHC h [b][n][512]: per-slice partial sums reduced in
// LDS, then atomicAdd into per-channel totals PsT/Ps2T (zeroed by wprep).
// ---------------------------------------------------------------------------
__global__ __launch_bounds__(256) void in_stats(
    const unsigned short* __restrict__ H, float* __restrict__ PsT,
    float* __restrict__ Ps2T, int N)
{
  const int cg = blockIdx.x, ns = blockIdx.y, b = blockIdx.z, t = threadIdx.x;
  const int c0 = cg * 64 + (t & 7) * 8;
  float s[8] = {}, s2[8] = {};
  #pragma unroll
  for (int i = 0; i < 8; ++i) {
    const int n = ns * 256 + (t >> 3) + i * 32;
    const short8 hv = *(const short8*)&H[((size_t)b * N + n) * 512 + c0];
    #pragma unroll
    for (int j = 0; j < 8; ++j) {
      const float f = bf2f((unsigned short)hv[j]);
      s[j] += f; s2[j] += f * f;
    }
  }
  __shared__ float rs[32][64], rs2[32][64];
  #pragma unroll
  for (int j = 0; j < 8; ++j) {
    rs[t >> 3][(t & 7) * 8 + j] = s[j];
    rs2[t >> 3][(t & 7) * 8 + j] = s2[j];
  }
  __syncthreads();
  if (t < 64) {
    float a = 0.f, a2 = 0.f;
    #pragma unroll
    for (int r = 0; r < 32; ++r) { a += rs[r][t]; a2 += rs2[r][t]; }
    const int c = cg * 64 + t;
    atomicAdd(&PsT [(size_t)b * 512 + c], a);
    atomicAdd(&Ps2T[(size_t)b * 512 + c], a2);
  }
}

// ---------------------------------------------------------------------------
extern "C" void kernel_launch(void* const* d_in, const int* in_sizes, int n_in,
                              void* d_out, int out_size, void* d_ws, size_t ws_size,
                              hipStream_t stream)
{
  const int B = 2, D = 256, N = 4096;

  const float* x   = (const float*)d_in[0];
  const float* src = (const float*)d_in[1];
  const float* Wq  = (const float*)d_in[2];  const float* bq = (const float*)d_in[3];
  const float* Wk  = (const float*)d_in[4];  const float* bk = (const float*)d_in[5];
  const float* Wv  = (const float*)d_in[6];  const float* bv = (const float*)d_in[7];
  const float* Wm  = (const float*)d_in[8];  const float* bm = (const float*)d_in[9];
  const float* W1  = (const float*)d_in[10]; const float* b1 = (const float*)d_in[11];
  const float* W2  = (const float*)d_in[12]; const float* b2 = (const float*)d_in[13];
  float* out = (float*)d_out;

  char* ws = (char*)d_ws;
  const size_t MB = 1u << 20;
  unsigned short* xb  = (unsigned short*)(ws + 0 * MB);    // [b][n][256] bf16
  unsigned short* sb  = (unsigned short*)(ws + 4 * MB);
  unsigned short* qbf = (unsigned short*)(ws + 8 * MB);    // head-major NHC
  unsigned short* kbf = (unsigned short*)(ws + 12 * MB);
  unsigned short* vhb = (unsigned short*)(ws + 16 * MB);   // [b][h][d][n]
  unsigned short* atb = (unsigned short*)(ws + 20 * MB);   // head-major NHC
  // Opart (24..41 MB) temporally overlaps msb/hb (dead during attention)
  unsigned short* Opart = (unsigned short*)(ws + 24 * MB); // 16.78 MB bf16
  unsigned short* msb = (unsigned short*)(ws + 24 * MB);   // NHC 256 (post-combine)
  unsigned short* hb  = (unsigned short*)(ws + 28 * MB);   // [b][n][512] RAW h
  float* liPart = (float*)(ws + 41 * MB);                  // 524 KB
  unsigned short* wqkvb = (unsigned short*)(ws + 42 * MB); // [768][256]
  unsigned short* wmb = wqkvb + 768 * 256;
  unsigned short* w1b = wmb + 256 * 256;                   // [512][512]
  unsigned short* w2b = w1b + 512 * 512;                   // [256][512]
  float* biasb = (float*)(ws + 44 * MB);                   // 1792 floats
  float* PsT   = biasb + 2048;                             // [B][512] totals
  float* Ps2T  = PsT + 1024;                               // [B][512] totals

  const dim3 blk(256);

  tx_all<<<dim3(N / 32, D / 32, 2 * B), blk, 0, stream>>>(x, src, xb, sb, D, N);
  wprep<<<dim3(2568), blk, 0, stream>>>(Wq, Wk, Wv, Wm, W1, W2,
                                        bq, bk, bv, bm, b1, b2,
                                        wqkvb, wmb, w1b, w2b, biasb, PsT, Ps2T);

  // fused q/k/v: Co=768, o<256 reads xb (q), else sb (k,v)  [BN=64: 1536 blk]
  gemmT<64, false><<<dim3(N / 64, 12, B), blk, 0, stream>>>(
      wqkvb, biasb, xb, sb, qbf, kbf, vhb, nullptr, nullptr, 768, 256, 256, N, 1);

  attn_mfma<<<dim3(N / 128, 4, B * 4), blk, 0, stream>>>(
      qbf, kbf, vhb, Opart, liPart, N);
  attn_combine<<<dim3(N / 128, 4, B), blk, 0, stream>>>(Opart, liPart, atb, N);

  // message (cols head-major-permuted to match atb)  [BN=64: 512 blocks]
  gemmT<64, false><<<dim3(N / 64, 4, B), blk, 0, stream>>>(
      wmb, biasb + 768, atb, atb, msb, nullptr, nullptr, nullptr, nullptr,
      256, 256, 256, N, 0);

  // h = W1 @ [x; msg]  [BN=64: 1024 blocks] — writes RAW h
  gemmT<64, false><<<dim3(N / 64, 8, B), blk, 0, stream>>>(
      w1b, biasb + 1024, xb, msb, hb, nullptr, nullptr, nullptr, nullptr,
      512, 512, 256, N, 0);

  in_stats<<<dim3(8, 16, B), blk, 0, stream>>>(hb, PsT, Ps2T, N);

  // out = W2 @ relu(norm(h)) — norm fused into X frags  [BN=64: 512 blocks]
  gemmT<64, true><<<dim3(N / 64, 4, B), blk, 0, stream>>>(
      w2b, biasb + 1536, hb, hb, out, nullptr, nullptr, PsT, Ps2T,
      256, 512, 512, N, 2);
}